// Round 1
// baseline (3854.413 us; speedup 1.0000x reference)
//
#include <hip/hip_runtime.h>

#define T_TOK 8192
#define DIM 768
#define DIN 1536
#define NST 16
#define RKK 48
#define NLAY 2
#define NSEG 4
#define LSEGC 2048
#define EPSF 1e-5f

typedef __attribute__((ext_vector_type(4))) float f32x4;
typedef __attribute__((ext_vector_type(8))) short bf16x8;

__device__ __forceinline__ short f2bf(float x) {
  union { float f; unsigned u; } c; c.f = x;
  unsigned r = (c.u + 0x7fffu + ((c.u >> 16) & 1u)) >> 16;
  return (short)r;
}

__device__ __forceinline__ float wave_sum(float v) {
#pragma unroll
  for (int o = 32; o > 0; o >>= 1) v += __shfl_xor(v, o, 64);
  return v;
}

// block = 256 threads (4 waves)
__device__ __forceinline__ float block_sum(float v, float* sbuf) {
  v = wave_sum(v);
  int w = threadIdx.x >> 6;
  if ((threadIdx.x & 63) == 0) sbuf[w] = v;
  __syncthreads();
  return sbuf[0] + sbuf[1] + sbuf[2] + sbuf[3];
}

__global__ void embed_rms_k(const int* __restrict__ tok, const float* __restrict__ emb,
                            const float* __restrict__ w, float* __restrict__ out) {
  __shared__ float sb[4];
  int t = blockIdx.x, tid = threadIdx.x;
  const float* row = emb + (size_t)tok[t] * DIM;
  float v0 = row[tid], v1 = row[tid + 256], v2 = row[tid + 512];
  float ss = block_sum(v0 * v0 + v1 * v1 + v2 * v2, sb);
  float rs = rsqrtf(ss * (1.f / DIM) + EPSF);
  float* o = out + (size_t)t * DIM;
  o[tid] = v0 * rs * w[tid];
  o[tid + 256] = v1 * rs * w[tid + 256];
  o[tid + 512] = v2 * rs * w[tid + 512];
}

__global__ void rms_k(const float* __restrict__ x, const float* __restrict__ w,
                      float* __restrict__ out) {
  __shared__ float sb[4];
  int t = blockIdx.x, tid = threadIdx.x;
  const float* row = x + (size_t)t * DIM;
  float v0 = row[tid], v1 = row[tid + 256], v2 = row[tid + 512];
  float ss = block_sum(v0 * v0 + v1 * v1 + v2 * v2, sb);
  float rs = rsqrtf(ss * (1.f / DIM) + EPSF);
  float* o = out + (size_t)t * DIM;
  o[tid] = v0 * rs * w[tid];
  o[tid + 256] = v1 * rs * w[tid + 256];
  o[tid + 512] = v2 * rs * w[tid + 512];
}

__global__ void final_norm_k(const float* __restrict__ c, const float* __restrict__ wf,
                             const float* __restrict__ wo, float* __restrict__ out) {
  __shared__ float sb1[4];
  __shared__ float sb2[4];
  int t = blockIdx.x, tid = threadIdx.x;
  const float* row = c + (size_t)t * DIM;
  float v0 = row[tid], v1 = row[tid + 256], v2 = row[tid + 512];
  float ss = block_sum(v0 * v0 + v1 * v1 + v2 * v2, sb1);
  float rs = rsqrtf(ss * (1.f / DIM) + EPSF);
  float y0 = v0 * rs * wf[tid], y1 = v1 * rs * wf[tid + 256], y2 = v2 * rs * wf[tid + 512];
  float ss2 = block_sum(y0 * y0 + y1 * y1 + y2 * y2, sb2);
  float rs2 = rsqrtf(ss2 * (1.f / DIM) + EPSF);
  float* o = out + (size_t)t * DIM;
  o[tid] = y0 * rs2 * wo[tid];
  o[tid + 256] = y1 * rs2 * wo[tid + 256];
  o[tid + 512] = y2 * rs2 * wo[tid + 512];
}

// ---------------- MFMA NT GEMM: C[M][N] = A[M][K] * W[N][K]^T ----------------
// EPI: 0 = plain store, 1 = += aux (residual, same layout as C), 2 = softplus(acc + aux[col])
#define BM 128
#define BN 128
#define BKG 64
#define LDSK 72

template <int EPI>
__global__ __launch_bounds__(256) void gemm_nt(const float* __restrict__ A, int lda,
                                               const float* __restrict__ W, int ldw,
                                               float* C, int ldc, int N, int K,
                                               const float* aux) {
  __shared__ short As[BM * LDSK];
  __shared__ short Ws[BN * LDSK];
  const int tid = threadIdx.x;
  const int lane = tid & 63;
  const int wave = tid >> 6;
  const int bm = blockIdx.x * BM;
  const int bn = blockIdx.y * BN;
  const int wr = (wave >> 1) * 64;
  const int wc = (wave & 1) * 64;
  const int srow = tid >> 1;
  const int scol = (tid & 1) * 32;

  f32x4 acc[4][4];
#pragma unroll
  for (int m = 0; m < 4; ++m)
#pragma unroll
    for (int n = 0; n < 4; ++n) acc[m][n] = (f32x4){0.f, 0.f, 0.f, 0.f};

  for (int k0 = 0; k0 < K; k0 += BKG) {
    // stage A tile (rows always valid: M multiple of BM)
    {
      const float* src = A + (size_t)(bm + srow) * lda + k0 + scol;
      short* dst = As + srow * LDSK + scol;
      if (k0 + BKG <= K) {
#pragma unroll
        for (int j = 0; j < 32; j += 4) {
          float4 v = *reinterpret_cast<const float4*>(src + j);
          short4 p;
          p.x = f2bf(v.x); p.y = f2bf(v.y); p.z = f2bf(v.z); p.w = f2bf(v.w);
          *reinterpret_cast<short4*>(dst + j) = p;
        }
      } else {
#pragma unroll
        for (int j = 0; j < 32; ++j) {
          int kk = k0 + scol + j;
          dst[j] = f2bf(kk < K ? src[j] : 0.f);
        }
      }
    }
    // stage W tile (guard rows vs N, cols vs K)
    {
      int rowW = bn + srow;
      const float* src = W + (size_t)rowW * ldw + k0 + scol;
      short* dst = Ws + srow * LDSK + scol;
      if (rowW < N && k0 + BKG <= K) {
#pragma unroll
        for (int j = 0; j < 32; j += 4) {
          float4 v = *reinterpret_cast<const float4*>(src + j);
          short4 p;
          p.x = f2bf(v.x); p.y = f2bf(v.y); p.z = f2bf(v.z); p.w = f2bf(v.w);
          *reinterpret_cast<short4*>(dst + j) = p;
        }
      } else {
#pragma unroll
        for (int j = 0; j < 32; ++j) {
          int kk = k0 + scol + j;
          float x = (rowW < N && kk < K) ? src[j] : 0.f;
          dst[j] = f2bf(x);
        }
      }
    }
    __syncthreads();

#pragma unroll
    for (int ks = 0; ks < BKG; ks += 32) {
      const int r = lane & 15;
      const int kq = ks + ((lane >> 4) << 3);
      bf16x8 af[4], wf[4];
#pragma unroll
      for (int m = 0; m < 4; ++m)
        af[m] = *reinterpret_cast<const bf16x8*>(&As[(wr + m * 16 + r) * LDSK + kq]);
#pragma unroll
      for (int n = 0; n < 4; ++n)
        wf[n] = *reinterpret_cast<const bf16x8*>(&Ws[(wc + n * 16 + r) * LDSK + kq]);
#pragma unroll
      for (int m = 0; m < 4; ++m)
#pragma unroll
        for (int n = 0; n < 4; ++n)
          acc[m][n] = __builtin_amdgcn_mfma_f32_16x16x32_bf16(af[m], wf[n], acc[m][n], 0, 0, 0);
    }
    __syncthreads();
  }

  const int r4 = (lane >> 4) * 4;
  const int cl = lane & 15;
#pragma unroll
  for (int m = 0; m < 4; ++m) {
    const int row0 = bm + wr + m * 16 + r4;
#pragma unroll
    for (int n = 0; n < 4; ++n) {
      const int col = bn + wc + n * 16 + cl;
      if (col < N) {
#pragma unroll
        for (int r = 0; r < 4; ++r) {
          float v = acc[m][n][r];
          size_t idx = (size_t)(row0 + r) * ldc + col;
          if (EPI == 1) v += aux[idx];
          if (EPI == 2) {
            v += aux[col];
            v = (v > 20.f) ? v : log1pf(__expf(v));
          }
          C[idx] = v;
        }
      }
    }
  }
}

// ---------------- depthwise causal conv (k=4) + bias + silu ----------------
__global__ void conv_k(const float* __restrict__ hz, const float* __restrict__ cw,
                       const float* __restrict__ cb, float* __restrict__ out) {
  int d = blockIdx.x * 256 + threadIdx.x;
  int t = blockIdx.y;
  int tl = t & (LSEGC - 1);
  float s = cb[d];
  const float* col = hz + (size_t)t * (2 * DIN) + d;
#pragma unroll
  for (int k = 0; k < 4; ++k) {
    int ts = tl - 3 + k;
    if (ts >= 0) s += col[(ptrdiff_t)(k - 3) * (2 * DIN)] * cw[d * 4 + k];
  }
  out[(size_t)t * DIN + d] = s / (1.f + __expf(-s));
}

// ---------------- selective scan: thread per (subject, channel) ----------------
__global__ __launch_bounds__(256) void scan_k(const float* __restrict__ dtv,
                                              const float* __restrict__ xv,
                                              const float* __restrict__ ssm,
                                              const float* __restrict__ hz,
                                              const float* __restrict__ A_log,
                                              const float* __restrict__ Dsk,
                                              float* __restrict__ yout) {
  __shared__ float bc[64][32];  // per step: B[16], C[16]
  const int tid = threadIdx.x;
  const int d = blockIdx.x * 256 + tid;
  const int s = blockIdx.y;
  const int t0 = s * LSEGC;

  float Areg[NST];
#pragma unroll
  for (int n = 0; n < NST; ++n) Areg[n] = -__expf(A_log[d * NST + n]);
  const float dsk = Dsk[d];

  float st[NST];
#pragma unroll
  for (int n = 0; n < NST; ++n) st[n] = 0.f;

  for (int c0 = 0; c0 < LSEGC; c0 += 64) {
    __syncthreads();
#pragma unroll
    for (int rr = 0; rr < 2; ++rr) {
      int i = tid + rr * 256;
      int step = i >> 3, part = i & 7;
      float4 v = *reinterpret_cast<const float4*>(ssm + (size_t)(t0 + c0 + step) * 80 + 48 + part * 4);
      *reinterpret_cast<float4*>(&bc[step][part * 4]) = v;
    }
    __syncthreads();

    size_t base = (size_t)(t0 + c0) * DIN + d;
    float dt_c = dtv[base], x_c = xv[base];
    float z_c = hz[(size_t)(t0 + c0) * (2 * DIN) + DIN + d];
    for (int tt = 0; tt < 64; ++tt) {
      float dt_n = 0.f, x_n = 0.f, z_n = 0.f;
      if (tt < 63) {
        size_t b2 = base + (size_t)(tt + 1) * DIN;
        dt_n = dtv[b2];
        x_n = xv[b2];
        z_n = hz[(size_t)(t0 + c0 + tt + 1) * (2 * DIN) + DIN + d];
      }
      float dtx = dt_c * x_c;
      const float* br = bc[tt];
      float y = 0.f;
#pragma unroll
      for (int n = 0; n < NST; ++n) {
        float decay = __expf(dt_c * Areg[n]);
        st[n] = st[n] * decay + dtx * br[n];
        y += st[n] * br[16 + n];
      }
      float sz = z_c / (1.f + __expf(-z_c));
      yout[base + (size_t)tt * DIN] = (y + x_c * dsk) * sz;
      dt_c = dt_n; x_c = x_n; z_c = z_n;
    }
  }
}

extern "C" void kernel_launch(void* const* d_in, const int* in_sizes, int n_in,
                              void* d_out, int out_size, void* d_ws, size_t ws_size,
                              hipStream_t stream) {
  const int* tokens = (const int*)d_in[0];
  // d_in[1] = subject_lengths (unused by the reference computation)
  const float* embed = (const float*)d_in[2];
  const float* in_norm_w = (const float*)d_in[3];
  const float* out_norm_w = (const float*)d_in[4];
  const float* norm_f_w = (const float*)d_in[5];
  const float* ln_w = (const float*)d_in[6];
  const float* in_w = (const float*)d_in[7];
  const float* conv_w = (const float*)d_in[8];
  const float* conv_b = (const float*)d_in[9];
  const float* xp_w = (const float*)d_in[10];
  const float* dt_w = (const float*)d_in[11];
  const float* dt_b = (const float*)d_in[12];
  const float* A_log = (const float*)d_in[13];
  const float* D_skip = (const float*)d_in[14];
  const float* out_w = (const float*)d_in[15];
  float* out = (float*)d_out;

  float* ws = (float*)d_ws;
  float* c = ws;                     // 8192*768
  float* xn = c + 6291456;           // 8192*768
  float* hz = xn + 6291456;          // 8192*3072
  float* hconv = hz + 25165824;      // 8192*1536
  float* ssm = hconv + 12582912;     // 8192*80
  float* dtv = ssm + 655360;         // 8192*1536
  float* yout = dtv + 12582912;      // 8192*1536

  embed_rms_k<<<T_TOK, 256, 0, stream>>>(tokens, embed, in_norm_w, c);

  for (int l = 0; l < NLAY; ++l) {
    rms_k<<<T_TOK, 256, 0, stream>>>(c, ln_w + l * DIM, xn);
    gemm_nt<0><<<dim3(T_TOK / BM, (2 * DIN) / BN), 256, 0, stream>>>(
        xn, DIM, in_w + (size_t)l * 2 * DIN * DIM, DIM, hz, 2 * DIN, 2 * DIN, DIM, nullptr);
    conv_k<<<dim3(DIN / 256, T_TOK), 256, 0, stream>>>(
        hz, conv_w + l * DIN * 4, conv_b + l * DIN, hconv);
    gemm_nt<0><<<dim3(T_TOK / BM, 1), 256, 0, stream>>>(
        hconv, DIN, xp_w + (size_t)l * (RKK + 2 * NST) * DIN, DIN, ssm, RKK + 2 * NST,
        RKK + 2 * NST, DIN, nullptr);
    gemm_nt<2><<<dim3(T_TOK / BM, DIN / BN), 256, 0, stream>>>(
        ssm, RKK + 2 * NST, dt_w + (size_t)l * DIN * RKK, RKK, dtv, DIN, DIN, RKK,
        dt_b + l * DIN);
    scan_k<<<dim3(DIN / 256, NSEG), 256, 0, stream>>>(
        dtv, hconv, ssm, hz, A_log + (size_t)l * DIN * NST, D_skip + l * DIN, yout);
    gemm_nt<1><<<dim3(T_TOK / BM, DIM / BN), 256, 0, stream>>>(
        yout, DIN, out_w + (size_t)l * DIM * DIN, DIN, c, DIM, DIM, DIN, c);
  }

  final_norm_k<<<T_TOK, 256, 0, stream>>>(c, norm_f_w, out_norm_w, out);
}

// Round 2
// 1409.200 us; speedup vs baseline: 2.7352x; 2.7352x over previous
//
#include <hip/hip_runtime.h>

#define T_TOK 8192
#define DIM 768
#define DIN 1536
#define NST 16
#define RKK 48
#define NLAY 2
#define NSEG 4
#define LSEGC 2048
#define EPSF 1e-5f
#define CHUNK 64
#define NCH (LSEGC / CHUNK)

typedef __attribute__((ext_vector_type(4))) float f32x4;
typedef __attribute__((ext_vector_type(8))) short bf16x8;

__device__ __forceinline__ short f2bf(float x) {
  union { float f; unsigned u; } c; c.f = x;
  unsigned r = (c.u + 0x7fffu + ((c.u >> 16) & 1u)) >> 16;
  return (short)r;
}

__device__ __forceinline__ float wave_sum(float v) {
#pragma unroll
  for (int o = 32; o > 0; o >>= 1) v += __shfl_xor(v, o, 64);
  return v;
}

__device__ __forceinline__ float block_sum(float v, float* sbuf) {
  v = wave_sum(v);
  int w = threadIdx.x >> 6;
  if ((threadIdx.x & 63) == 0) sbuf[w] = v;
  __syncthreads();
  return sbuf[0] + sbuf[1] + sbuf[2] + sbuf[3];
}

__global__ void embed_rms_k(const int* __restrict__ tok, const float* __restrict__ emb,
                            const float* __restrict__ w, float* __restrict__ out) {
  __shared__ float sb[4];
  int t = blockIdx.x, tid = threadIdx.x;
  const float* row = emb + (size_t)tok[t] * DIM;
  float v0 = row[tid], v1 = row[tid + 256], v2 = row[tid + 512];
  float ss = block_sum(v0 * v0 + v1 * v1 + v2 * v2, sb);
  float rs = rsqrtf(ss * (1.f / DIM) + EPSF);
  float* o = out + (size_t)t * DIM;
  o[tid] = v0 * rs * w[tid];
  o[tid + 256] = v1 * rs * w[tid + 256];
  o[tid + 512] = v2 * rs * w[tid + 512];
}

__global__ void rms_k(const float* __restrict__ x, const float* __restrict__ w,
                      float* __restrict__ out) {
  __shared__ float sb[4];
  int t = blockIdx.x, tid = threadIdx.x;
  const float* row = x + (size_t)t * DIM;
  float v0 = row[tid], v1 = row[tid + 256], v2 = row[tid + 512];
  float ss = block_sum(v0 * v0 + v1 * v1 + v2 * v2, sb);
  float rs = rsqrtf(ss * (1.f / DIM) + EPSF);
  float* o = out + (size_t)t * DIM;
  o[tid] = v0 * rs * w[tid];
  o[tid + 256] = v1 * rs * w[tid + 256];
  o[tid + 512] = v2 * rs * w[tid + 512];
}

__global__ void final_norm_k(const float* __restrict__ c, const float* __restrict__ wf,
                             const float* __restrict__ wo, float* __restrict__ out) {
  __shared__ float sb1[4];
  __shared__ float sb2[4];
  int t = blockIdx.x, tid = threadIdx.x;
  const float* row = c + (size_t)t * DIM;
  float v0 = row[tid], v1 = row[tid + 256], v2 = row[tid + 512];
  float ss = block_sum(v0 * v0 + v1 * v1 + v2 * v2, sb1);
  float rs = rsqrtf(ss * (1.f / DIM) + EPSF);
  float y0 = v0 * rs * wf[tid], y1 = v1 * rs * wf[tid + 256], y2 = v2 * rs * wf[tid + 512];
  float ss2 = block_sum(y0 * y0 + y1 * y1 + y2 * y2, sb2);
  float rs2 = rsqrtf(ss2 * (1.f / DIM) + EPSF);
  float* o = out + (size_t)t * DIM;
  o[tid] = y0 * rs2 * wo[tid];
  o[tid + 256] = y1 * rs2 * wo[tid + 256];
  o[tid + 512] = y2 * rs2 * wo[tid + 512];
}

// ---------------- MFMA NT GEMM: C[M][N] = A[M][K] * W[N][K]^T ----------------
#define BM 128
#define BN 128
#define BKG 64
#define LDSK 72

template <int EPI>
__global__ __launch_bounds__(256) void gemm_nt(const float* __restrict__ A, int lda,
                                               const float* __restrict__ W, int ldw,
                                               float* C, int ldc, int N, int K,
                                               const float* aux) {
  __shared__ short As[BM * LDSK];
  __shared__ short Ws[BN * LDSK];
  const int tid = threadIdx.x;
  const int lane = tid & 63;
  const int wave = tid >> 6;
  const int bm = blockIdx.x * BM;
  const int bn = blockIdx.y * BN;
  const int wr = (wave >> 1) * 64;
  const int wc = (wave & 1) * 64;
  const int srow = tid >> 1;
  const int scol = (tid & 1) * 32;

  f32x4 acc[4][4];
#pragma unroll
  for (int m = 0; m < 4; ++m)
#pragma unroll
    for (int n = 0; n < 4; ++n) acc[m][n] = (f32x4){0.f, 0.f, 0.f, 0.f};

  for (int k0 = 0; k0 < K; k0 += BKG) {
    {
      const float* src = A + (size_t)(bm + srow) * lda + k0 + scol;
      short* dst = As + srow * LDSK + scol;
      if (k0 + BKG <= K) {
#pragma unroll
        for (int j = 0; j < 32; j += 4) {
          float4 v = *reinterpret_cast<const float4*>(src + j);
          short4 p;
          p.x = f2bf(v.x); p.y = f2bf(v.y); p.z = f2bf(v.z); p.w = f2bf(v.w);
          *reinterpret_cast<short4*>(dst + j) = p;
        }
      } else {
#pragma unroll
        for (int j = 0; j < 32; ++j) {
          int kk = k0 + scol + j;
          dst[j] = f2bf(kk < K ? src[j] : 0.f);
        }
      }
    }
    {
      int rowW = bn + srow;
      const float* src = W + (size_t)rowW * ldw + k0 + scol;
      short* dst = Ws + srow * LDSK + scol;
      if (rowW < N && k0 + BKG <= K) {
#pragma unroll
        for (int j = 0; j < 32; j += 4) {
          float4 v = *reinterpret_cast<const float4*>(src + j);
          short4 p;
          p.x = f2bf(v.x); p.y = f2bf(v.y); p.z = f2bf(v.z); p.w = f2bf(v.w);
          *reinterpret_cast<short4*>(dst + j) = p;
        }
      } else {
#pragma unroll
        for (int j = 0; j < 32; ++j) {
          int kk = k0 + scol + j;
          float x = (rowW < N && kk < K) ? src[j] : 0.f;
          dst[j] = f2bf(x);
        }
      }
    }
    __syncthreads();

#pragma unroll
    for (int ks = 0; ks < BKG; ks += 32) {
      const int r = lane & 15;
      const int kq = ks + ((lane >> 4) << 3);
      bf16x8 af[4], wf[4];
#pragma unroll
      for (int m = 0; m < 4; ++m)
        af[m] = *reinterpret_cast<const bf16x8*>(&As[(wr + m * 16 + r) * LDSK + kq]);
#pragma unroll
      for (int n = 0; n < 4; ++n)
        wf[n] = *reinterpret_cast<const bf16x8*>(&Ws[(wc + n * 16 + r) * LDSK + kq]);
#pragma unroll
      for (int m = 0; m < 4; ++m)
#pragma unroll
        for (int n = 0; n < 4; ++n)
          acc[m][n] = __builtin_amdgcn_mfma_f32_16x16x32_bf16(af[m], wf[n], acc[m][n], 0, 0, 0);
    }
    __syncthreads();
  }

  const int r4 = (lane >> 4) * 4;
  const int cl = lane & 15;
#pragma unroll
  for (int m = 0; m < 4; ++m) {
    const int row0 = bm + wr + m * 16 + r4;
#pragma unroll
    for (int n = 0; n < 4; ++n) {
      const int col = bn + wc + n * 16 + cl;
      if (col < N) {
#pragma unroll
        for (int r = 0; r < 4; ++r) {
          float v = acc[m][n][r];
          size_t idx = (size_t)(row0 + r) * ldc + col;
          if (EPI == 1) v += aux[idx];
          if (EPI == 2) {
            v += aux[col];
            v = (v > 20.f) ? v : log1pf(__expf(v));
          }
          C[idx] = v;
        }
      }
    }
  }
}

// ---------------- depthwise causal conv (k=4) + bias + silu ----------------
__global__ void conv_k(const float* __restrict__ hz, const float* __restrict__ cw,
                       const float* __restrict__ cb, float* __restrict__ out) {
  int d = blockIdx.x * 256 + threadIdx.x;
  int t = blockIdx.y;
  int tl = t & (LSEGC - 1);
  float s = cb[d];
  const float* col = hz + (size_t)t * (2 * DIN) + d;
#pragma unroll
  for (int k = 0; k < 4; ++k) {
    int ts = tl - 3 + k;
    if (ts >= 0) s += col[(ptrdiff_t)(k - 3) * (2 * DIN)] * cw[d * 4 + k];
  }
  out[(size_t)t * DIN + d] = s / (1.f + __expf(-s));
}

// ---------------- chunked selective scan ----------------
// Phase 1: per-chunk local scan from zero state; emit final local state + sum(dt).
__global__ __launch_bounds__(256) void scan_p1(const float* __restrict__ dtv,
                                               const float* __restrict__ xv,
                                               const float* __restrict__ ssm,
                                               const float* __restrict__ A_log,
                                               float* __restrict__ cstate,
                                               float* __restrict__ csumdt) {
  __shared__ float bsh[CHUNK][16];
  const int tid = threadIdx.x;
  const int d = blockIdx.x * 256 + tid;
  const int s = blockIdx.y;
  const int ch = blockIdx.z;
  const int t0 = s * LSEGC + ch * CHUNK;

  {  // stage B: 64 steps x 16 floats, each thread loads 4
    int step = tid >> 2, part = tid & 3;
    float4 v = *reinterpret_cast<const float4*>(ssm + (size_t)(t0 + step) * 80 + 48 + part * 4);
    *reinterpret_cast<float4*>(&bsh[step][part * 4]) = v;
  }
  __syncthreads();

  float Areg[NST];
#pragma unroll
  for (int n = 0; n < NST; ++n) Areg[n] = -__expf(A_log[d * NST + n]);
  float st[NST];
#pragma unroll
  for (int n = 0; n < NST; ++n) st[n] = 0.f;
  float sumdt = 0.f;

  size_t base = (size_t)t0 * DIN + d;
  float dt_c = dtv[base], x_c = xv[base];
  for (int tt = 0; tt < CHUNK; ++tt) {
    float dt_n = 0.f, x_n = 0.f;
    if (tt < CHUNK - 1) {
      size_t b2 = base + (size_t)(tt + 1) * DIN;
      dt_n = dtv[b2];
      x_n = xv[b2];
    }
    sumdt += dt_c;
    float dtx = dt_c * x_c;
    const float* br = bsh[tt];
#pragma unroll
    for (int n = 0; n < NST; ++n) {
      st[n] = st[n] * __expf(dt_c * Areg[n]) + dtx * br[n];
    }
    dt_c = dt_n; x_c = x_n;
  }

  size_t cidx = (((size_t)s * NCH + ch) * DIN + d) * NST;
#pragma unroll
  for (int n = 0; n < NST; n += 4)
    *reinterpret_cast<f32x4*>(cstate + cidx + n) = (f32x4){st[n], st[n+1], st[n+2], st[n+3]};
  csumdt[((size_t)s * NCH + ch) * DIN + d] = sumdt;
}

// Phase 2: sequential combine across chunks; overwrite cstate with INCOMING state.
__global__ __launch_bounds__(256) void scan_p2(const float* __restrict__ A_log,
                                               const float* __restrict__ csumdt,
                                               float* __restrict__ cstate) {
  int idx = blockIdx.x * 256 + threadIdx.x;  // ((s*DIN)+d)*NST + n
  int n = idx & (NST - 1);
  int d = (idx / NST) % DIN;
  int s = idx / (DIN * NST);
  float A = -__expf(A_log[d * NST + n]);
  float H = 0.f;
  for (int c = 0; c < NCH; ++c) {
    size_t off = (((size_t)s * NCH + c) * DIN + d) * NST + n;
    float loc = cstate[off];
    float sd = csumdt[((size_t)s * NCH + c) * DIN + d];
    cstate[off] = H;
    H = H * __expf(A * sd) + loc;
  }
}

// Phase 3: exact per-chunk scan seeded with incoming state; full epilogue.
__global__ __launch_bounds__(256) void scan_p3(const float* __restrict__ dtv,
                                               const float* __restrict__ xv,
                                               const float* __restrict__ ssm,
                                               const float* __restrict__ hz,
                                               const float* __restrict__ A_log,
                                               const float* __restrict__ Dsk,
                                               const float* __restrict__ cstate,
                                               float* __restrict__ yout) {
  __shared__ float bc[CHUNK][32];
  const int tid = threadIdx.x;
  const int d = blockIdx.x * 256 + tid;
  const int s = blockIdx.y;
  const int ch = blockIdx.z;
  const int t0 = s * LSEGC + ch * CHUNK;

#pragma unroll
  for (int rr = 0; rr < 2; ++rr) {  // stage B+C: 64 steps x 32 floats
    int i = tid + rr * 256;
    int step = i >> 3, part = i & 7;
    float4 v = *reinterpret_cast<const float4*>(ssm + (size_t)(t0 + step) * 80 + 48 + part * 4);
    *reinterpret_cast<float4*>(&bc[step][part * 4]) = v;
  }
  __syncthreads();

  float Areg[NST];
#pragma unroll
  for (int n = 0; n < NST; ++n) Areg[n] = -__expf(A_log[d * NST + n]);
  const float dsk = Dsk[d];

  float st[NST];
  size_t cidx = (((size_t)s * NCH + ch) * DIN + d) * NST;
#pragma unroll
  for (int n = 0; n < NST; n += 4) {
    f32x4 v = *reinterpret_cast<const f32x4*>(cstate + cidx + n);
    st[n] = v[0]; st[n+1] = v[1]; st[n+2] = v[2]; st[n+3] = v[3];
  }

  size_t base = (size_t)t0 * DIN + d;
  float dt_c = dtv[base], x_c = xv[base];
  float z_c = hz[(size_t)t0 * (2 * DIN) + DIN + d];
  for (int tt = 0; tt < CHUNK; ++tt) {
    float dt_n = 0.f, x_n = 0.f, z_n = 0.f;
    if (tt < CHUNK - 1) {
      size_t b2 = base + (size_t)(tt + 1) * DIN;
      dt_n = dtv[b2];
      x_n = xv[b2];
      z_n = hz[(size_t)(t0 + tt + 1) * (2 * DIN) + DIN + d];
    }
    float dtx = dt_c * x_c;
    const float* br = bc[tt];
    float y = 0.f;
#pragma unroll
    for (int n = 0; n < NST; ++n) {
      st[n] = st[n] * __expf(dt_c * Areg[n]) + dtx * br[n];
      y += st[n] * br[16 + n];
    }
    float sz = z_c / (1.f + __expf(-z_c));
    yout[base + (size_t)tt * DIN] = (y + x_c * dsk) * sz;
    dt_c = dt_n; x_c = x_n; z_c = z_n;
  }
}

extern "C" void kernel_launch(void* const* d_in, const int* in_sizes, int n_in,
                              void* d_out, int out_size, void* d_ws, size_t ws_size,
                              hipStream_t stream) {
  const int* tokens = (const int*)d_in[0];
  const float* embed = (const float*)d_in[2];
  const float* in_norm_w = (const float*)d_in[3];
  const float* out_norm_w = (const float*)d_in[4];
  const float* norm_f_w = (const float*)d_in[5];
  const float* ln_w = (const float*)d_in[6];
  const float* in_w = (const float*)d_in[7];
  const float* conv_w = (const float*)d_in[8];
  const float* conv_b = (const float*)d_in[9];
  const float* xp_w = (const float*)d_in[10];
  const float* dt_w = (const float*)d_in[11];
  const float* dt_b = (const float*)d_in[12];
  const float* A_log = (const float*)d_in[13];
  const float* D_skip = (const float*)d_in[14];
  const float* out_w = (const float*)d_in[15];
  float* out = (float*)d_out;

  float* ws = (float*)d_ws;
  float* c = ws;                     // 8192*768
  float* xn = c + 6291456;           // 8192*768 (also reused as scan scratch)
  float* hz = xn + 6291456;          // 8192*3072
  float* hconv = hz + 25165824;      // 8192*1536
  float* ssm = hconv + 12582912;     // 8192*80
  float* dtv = ssm + 655360;         // 8192*1536
  float* yout = dtv + 12582912;      // 8192*1536

  float* cstate = xn;                // NSEG*NCH*DIN*NST = 3,145,728 floats
  float* csumdt = xn + 3145728;      // NSEG*NCH*DIN     =   196,608 floats

  embed_rms_k<<<T_TOK, 256, 0, stream>>>(tokens, embed, in_norm_w, c);

  for (int l = 0; l < NLAY; ++l) {
    rms_k<<<T_TOK, 256, 0, stream>>>(c, ln_w + l * DIM, xn);
    gemm_nt<0><<<dim3(T_TOK / BM, (2 * DIN) / BN), 256, 0, stream>>>(
        xn, DIM, in_w + (size_t)l * 2 * DIN * DIM, DIM, hz, 2 * DIN, 2 * DIN, DIM, nullptr);
    conv_k<<<dim3(DIN / 256, T_TOK), 256, 0, stream>>>(
        hz, conv_w + l * DIN * 4, conv_b + l * DIN, hconv);
    gemm_nt<0><<<dim3(T_TOK / BM, 1), 256, 0, stream>>>(
        hconv, DIN, xp_w + (size_t)l * (RKK + 2 * NST) * DIN, DIN, ssm, RKK + 2 * NST,
        RKK + 2 * NST, DIN, nullptr);
    gemm_nt<2><<<dim3(T_TOK / BM, DIN / BN), 256, 0, stream>>>(
        ssm, RKK + 2 * NST, dt_w + (size_t)l * DIN * RKK, RKK, dtv, DIN, DIN, RKK,
        dt_b + l * DIN);
    scan_p1<<<dim3(DIN / 256, NSEG, NCH), 256, 0, stream>>>(
        dtv, hconv, ssm, A_log + (size_t)l * DIN * NST, cstate, csumdt);
    scan_p2<<<(NSEG * DIN * NST) / 256, 256, 0, stream>>>(
        A_log + (size_t)l * DIN * NST, csumdt, cstate);
    scan_p3<<<dim3(DIN / 256, NSEG, NCH), 256, 0, stream>>>(
        dtv, hconv, ssm, hz, A_log + (size_t)l * DIN * NST, D_skip + l * DIN, cstate, yout);
    gemm_nt<1><<<dim3(T_TOK / BM, DIM / BN), 256, 0, stream>>>(
        yout, DIN, out_w + (size_t)l * DIM * DIN, DIN, c, DIM, DIM, DIN, c);
  }

  final_norm_k<<<T_TOK, 256, 0, stream>>>(c, norm_f_w, out_norm_w, out);
}

// Round 7
// 1012.883 us; speedup vs baseline: 3.8054x; 1.3913x over previous
//
#include <hip/hip_runtime.h>

#define T_TOK 8192
#define DIM 768
#define DIN 1536
#define NST 16
#define RKK 48
#define NLAY 2
#define NSEG 4
#define LSEGC 2048
#define EPSF 1e-5f
#define CHUNK 64
#define NCH (LSEGC / CHUNK)

typedef __attribute__((ext_vector_type(4))) float f32x4;
typedef __attribute__((ext_vector_type(8))) short bf16x8;

__device__ __forceinline__ short f2bf(float x) {
  union { float f; unsigned u; } c; c.f = x;
  unsigned r = (c.u + 0x7fffu + ((c.u >> 16) & 1u)) >> 16;
  return (short)r;
}

__device__ __forceinline__ float bf2f(short s) {
  union { unsigned u; float f; } c;
  c.u = ((unsigned)(unsigned short)s) << 16;
  return c.f;
}

__device__ __forceinline__ float wave_sum(float v) {
#pragma unroll
  for (int o = 32; o > 0; o >>= 1) v += __shfl_xor(v, o, 64);
  return v;
}

__device__ __forceinline__ float block_sum(float v, float* sbuf) {
  v = wave_sum(v);
  int w = threadIdx.x >> 6;
  if ((threadIdx.x & 63) == 0) sbuf[w] = v;
  __syncthreads();
  return sbuf[0] + sbuf[1] + sbuf[2] + sbuf[3];
}

__global__ void embed_rms_k(const int* __restrict__ tok, const float* __restrict__ emb,
                            const float* __restrict__ w, float* __restrict__ out) {
  __shared__ float sb[4];
  int t = blockIdx.x, tid = threadIdx.x;
  const float* row = emb + (size_t)tok[t] * DIM;
  float v0 = row[tid], v1 = row[tid + 256], v2 = row[tid + 512];
  float ss = block_sum(v0 * v0 + v1 * v1 + v2 * v2, sb);
  float rs = rsqrtf(ss * (1.f / DIM) + EPSF);
  float* o = out + (size_t)t * DIM;
  o[tid] = v0 * rs * w[tid];
  o[tid + 256] = v1 * rs * w[tid + 256];
  o[tid + 512] = v2 * rs * w[tid + 512];
}

__global__ void rms_bf_k(const float* __restrict__ x, const float* __restrict__ w,
                         short* __restrict__ out) {
  __shared__ float sb[4];
  int t = blockIdx.x, tid = threadIdx.x;
  const float* row = x + (size_t)t * DIM;
  float v0 = row[tid], v1 = row[tid + 256], v2 = row[tid + 512];
  float ss = block_sum(v0 * v0 + v1 * v1 + v2 * v2, sb);
  float rs = rsqrtf(ss * (1.f / DIM) + EPSF);
  short* o = out + (size_t)t * DIM;
  o[tid] = f2bf(v0 * rs * w[tid]);
  o[tid + 256] = f2bf(v1 * rs * w[tid + 256]);
  o[tid + 512] = f2bf(v2 * rs * w[tid + 512]);
}

__global__ void final_norm_k(const float* __restrict__ c, const float* __restrict__ wf,
                             const float* __restrict__ wo, float* __restrict__ out) {
  __shared__ float sb1[4];
  __shared__ float sb2[4];
  int t = blockIdx.x, tid = threadIdx.x;
  const float* row = c + (size_t)t * DIM;
  float v0 = row[tid], v1 = row[tid + 256], v2 = row[tid + 512];
  float ss = block_sum(v0 * v0 + v1 * v1 + v2 * v2, sb1);
  float rs = rsqrtf(ss * (1.f / DIM) + EPSF);
  float y0 = v0 * rs * wf[tid], y1 = v1 * rs * wf[tid + 256], y2 = v2 * rs * wf[tid + 512];
  float ss2 = block_sum(y0 * y0 + y1 * y1 + y2 * y2, sb2);
  float rs2 = rsqrtf(ss2 * (1.f / DIM) + EPSF);
  float* o = out + (size_t)t * DIM;
  o[tid] = y0 * rs2 * wo[tid];
  o[tid + 256] = y1 * rs2 * wo[tid + 256];
  o[tid + 512] = y2 * rs2 * wo[tid + 512];
}

// weight f32 -> bf16 with zero padding to (drows, dcols)
__global__ void convw_k(const float* __restrict__ src, short* __restrict__ dst,
                        int rows, int cols, int drows, int dcols) {
  int i = blockIdx.x * 256 + threadIdx.x;
  if (i >= drows * dcols) return;
  int r = i / dcols, cc = i - r * dcols;
  float v = (r < rows && cc < cols) ? src[(size_t)r * cols + cc] : 0.f;
  dst[i] = f2bf(v);
}

// ------- MFMA NT GEMM, bf16 inputs, reg-staged LDS, both-sides XOR swizzle -------
// C[M][N] = A[M][K] * W[N][K]^T.  M mult of 128, K mult of 64, W rows padded to 128 mult.
// EPI 1: C f32 = acc + aux[idx] (residual)
// EPI 2: out2 bf16 = softplus(acc + aux[col])        (dt GEMM)
// EPI 3: C f32 (N=80) + out2 bf16 padded to 64 cols  (xp GEMM)
// EPI 4: split: col<DIN -> C f32 (h), else -> out2 bf16 (z)   (in GEMM)
#define BM 128
#define BN 128

template <int EPI>
__global__ __launch_bounds__(256) void gemm_bf(const short* __restrict__ A, int lda,
                                               const short* __restrict__ W, int ldw,
                                               float* __restrict__ C, int ldc, int N, int K,
                                               const float* __restrict__ aux,
                                               short* __restrict__ out2) {
  __shared__ short As[BM * 64];
  __shared__ short Ws[BN * 64];
  const int tid = threadIdx.x;
  const int lane = tid & 63;
  const int wave = tid >> 6;
  const int bm = blockIdx.x * BM;
  const int bn = blockIdx.y * BN;
  const int wr = (wave >> 1) * 64;
  const int wc = (wave & 1) * 64;
  const int srow = tid >> 1;            // 0..127
  const int sc8 = (tid & 1) * 4;        // chunk base 0 or 4 (chunks of 8 shorts)
  const int sx = srow & 7;              // row phase for XOR swizzle

  f32x4 acc[4][4];
#pragma unroll
  for (int m = 0; m < 4; ++m)
#pragma unroll
    for (int n = 0; n < 4; ++n) acc[m][n] = (f32x4){0.f, 0.f, 0.f, 0.f};

  const short* Ap = A + (size_t)(bm + srow) * lda + sc8 * 8;
  const short* Wp = W + (size_t)(bn + srow) * ldw + sc8 * 8;
  short* Asw = As + srow * 64;
  short* Wsw = Ws + srow * 64;

  for (int k0 = 0; k0 < K; k0 += 64) {
    bf16x8 av[4], wv[4];
#pragma unroll
    for (int j = 0; j < 4; ++j) av[j] = *reinterpret_cast<const bf16x8*>(Ap + k0 + j * 8);
#pragma unroll
    for (int j = 0; j < 4; ++j) wv[j] = *reinterpret_cast<const bf16x8*>(Wp + k0 + j * 8);
    if (k0) __syncthreads();  // prev readers done before overwrite
#pragma unroll
    for (int j = 0; j < 4; ++j)
      *reinterpret_cast<bf16x8*>(Asw + (((sc8 + j) ^ sx) << 3)) = av[j];
#pragma unroll
    for (int j = 0; j < 4; ++j)
      *reinterpret_cast<bf16x8*>(Wsw + (((sc8 + j) ^ sx) << 3)) = wv[j];
    __syncthreads();

    const int r = lane & 15;
    const int swz = (r & 7) << 3;
#pragma unroll
    for (int ks = 0; ks < 64; ks += 32) {
      const int kq = (ks + ((lane >> 4) << 3)) ^ swz;
      bf16x8 af[4], wf[4];
#pragma unroll
      for (int m = 0; m < 4; ++m)
        af[m] = *reinterpret_cast<const bf16x8*>(&As[(wr + m * 16 + r) * 64 + kq]);
#pragma unroll
      for (int n = 0; n < 4; ++n)
        wf[n] = *reinterpret_cast<const bf16x8*>(&Ws[(wc + n * 16 + r) * 64 + kq]);
#pragma unroll
      for (int m = 0; m < 4; ++m)
#pragma unroll
        for (int n = 0; n < 4; ++n)
          acc[m][n] = __builtin_amdgcn_mfma_f32_16x16x32_bf16(af[m], wf[n], acc[m][n], 0, 0, 0);
    }
    __syncthreads();
  }

  const int r4 = ((lane >> 4) & 3) * 4;
  const int cl = lane & 15;
#pragma unroll
  for (int m = 0; m < 4; ++m) {
    const int row0 = bm + wr + m * 16 + r4;
#pragma unroll
    for (int n = 0; n < 4; ++n) {
      const int col = bn + wc + n * 16 + cl;
#pragma unroll
      for (int r = 0; r < 4; ++r) {
        float v = acc[m][n][r];
        size_t row = (size_t)(row0 + r);
        if (EPI == 1) {
          size_t idx = row * ldc + col;
          C[idx] = v + aux[idx];
        } else if (EPI == 2) {
          v += aux[col];
          v = (v > 20.f) ? v : log1pf(__expf(v));
          out2[row * DIN + col] = f2bf(v);
        } else if (EPI == 3) {
          if (col < N) C[row * 80 + col] = v;
          if (col < 64) out2[row * 64 + col] = (col < RKK) ? f2bf(v) : 0;
        } else if (EPI == 4) {
          if (col < DIN) C[row * DIN + col] = v;
          else out2[row * DIN + col - DIN] = f2bf(v);
        }
      }
    }
  }
}

// ------- depthwise causal conv (k=4) + bias + silu; bf16 output -------
__global__ void conv_k(const float* __restrict__ h, const float* __restrict__ cw,
                       const float* __restrict__ cb, short* __restrict__ outb) {
  int d = blockIdx.x * 256 + threadIdx.x;
  int t = blockIdx.y;
  int tl = t & (LSEGC - 1);
  float s = cb[d];
  const float* col = h + (size_t)t * DIN + d;
#pragma unroll
  for (int k = 0; k < 4; ++k) {
    int ts = tl - 3 + k;
    if (ts >= 0) s += col[(ptrdiff_t)(k - 3) * DIN] * cw[d * 4 + k];
  }
  float y = s / (1.f + __expf(-s));
  outb[(size_t)t * DIN + d] = f2bf(y);
}

// ---------------- chunked selective scan (bf16 dt/x/z inputs) ----------------
__global__ __launch_bounds__(256) void scan_p1(const short* __restrict__ dtb,
                                               const short* __restrict__ xb,
                                               const float* __restrict__ ssm,
                                               const float* __restrict__ A_log,
                                               float* __restrict__ cstate,
                                               float* __restrict__ csumdt) {
  __shared__ float bsh[CHUNK][16];
  const int tid = threadIdx.x;
  const int d = blockIdx.x * 256 + tid;
  const int s = blockIdx.y;
  const int ch = blockIdx.z;
  const int t0 = s * LSEGC + ch * CHUNK;

  {
    int step = tid >> 2, part = tid & 3;
    float4 v = *reinterpret_cast<const float4*>(ssm + (size_t)(t0 + step) * 80 + 48 + part * 4);
    *reinterpret_cast<float4*>(&bsh[step][part * 4]) = v;
  }
  __syncthreads();

  float Areg[NST];
#pragma unroll
  for (int n = 0; n < NST; ++n) Areg[n] = -__expf(A_log[d * NST + n]);
  float st[NST];
#pragma unroll
  for (int n = 0; n < NST; ++n) st[n] = 0.f;
  float sumdt = 0.f;

  size_t base = (size_t)t0 * DIN + d;
  float dt_c = bf2f(dtb[base]), x_c = bf2f(xb[base]);
  for (int tt = 0; tt < CHUNK; ++tt) {
    float dt_n = 0.f, x_n = 0.f;
    if (tt < CHUNK - 1) {
      size_t b2 = base + (size_t)(tt + 1) * DIN;
      dt_n = bf2f(dtb[b2]);
      x_n = bf2f(xb[b2]);
    }
    sumdt += dt_c;
    float dtx = dt_c * x_c;
    const float* br = bsh[tt];
#pragma unroll
    for (int n = 0; n < NST; ++n) st[n] = st[n] * __expf(dt_c * Areg[n]) + dtx * br[n];
    dt_c = dt_n; x_c = x_n;
  }

  size_t cidx = (((size_t)s * NCH + ch) * DIN + d) * NST;
#pragma unroll
  for (int n = 0; n < NST; n += 4)
    *reinterpret_cast<f32x4*>(cstate + cidx + n) = (f32x4){st[n], st[n+1], st[n+2], st[n+3]};
  csumdt[((size_t)s * NCH + ch) * DIN + d] = sumdt;
}

__global__ __launch_bounds__(256) void scan_p2(const float* __restrict__ A_log,
                                               const float* __restrict__ csumdt,
                                               float* __restrict__ cstate) {
  int idx = blockIdx.x * 256 + threadIdx.x;
  int n = idx & (NST - 1);
  int d = (idx / NST) % DIN;
  int s = idx / (DIN * NST);
  float A = -__expf(A_log[d * NST + n]);
  float H = 0.f;
  for (int c = 0; c < NCH; ++c) {
    size_t off = (((size_t)s * NCH + c) * DIN + d) * NST + n;
    float loc = cstate[off];
    float sd = csumdt[((size_t)s * NCH + c) * DIN + d];
    cstate[off] = H;
    H = H * __expf(A * sd) + loc;
  }
}

__global__ __launch_bounds__(256) void scan_p3(const short* __restrict__ dtb,
                                               const short* __restrict__ xb,
                                               const float* __restrict__ ssm,
                                               const short* __restrict__ zb,
                                               const float* __restrict__ A_log,
                                               const float* __restrict__ Dsk,
                                               const float* __restrict__ cstate,
                                               short* __restrict__ yout) {
  __shared__ float bc[CHUNK][32];
  const int tid = threadIdx.x;
  const int d = blockIdx.x * 256 + tid;
  const int s = blockIdx.y;
  const int ch = blockIdx.z;
  const int t0 = s * LSEGC + ch * CHUNK;

#pragma unroll
  for (int rr = 0; rr < 2; ++rr) {
    int i = tid + rr * 256;
    int step = i >> 3, part = i & 7;
    float4 v = *reinterpret_cast<const float4*>(ssm + (size_t)(t0 + step) * 80 + 48 + part * 4);
    *reinterpret_cast<float4*>(&bc[step][part * 4]) = v;
  }
  __syncthreads();

  float Areg[NST];
#pragma unroll
  for (int n = 0; n < NST; ++n) Areg[n] = -__expf(A_log[d * NST + n]);
  const float dsk = Dsk[d];

  float st[NST];
  size_t cidx = (((size_t)s * NCH + ch) * DIN + d) * NST;
#pragma unroll
  for (int n = 0; n < NST; n += 4) {
    f32x4 v = *reinterpret_cast<const f32x4*>(cstate + cidx + n);
    st[n] = v[0]; st[n+1] = v[1]; st[n+2] = v[2]; st[n+3] = v[3];
  }

  size_t base = (size_t)t0 * DIN + d;
  float dt_c = bf2f(dtb[base]), x_c = bf2f(xb[base]), z_c = bf2f(zb[base]);
  for (int tt = 0; tt < CHUNK; ++tt) {
    float dt_n = 0.f, x_n = 0.f, z_n = 0.f;
    if (tt < CHUNK - 1) {
      size_t b2 = base + (size_t)(tt + 1) * DIN;
      dt_n = bf2f(dtb[b2]);
      x_n = bf2f(xb[b2]);
      z_n = bf2f(zb[b2]);
    }
    float dtx = dt_c * x_c;
    const float* br = bc[tt];
    float y = 0.f;
#pragma unroll
    for (int n = 0; n < NST; ++n) {
      st[n] = st[n] * __expf(dt_c * Areg[n]) + dtx * br[n];
      y += st[n] * br[16 + n];
    }
    float sz = z_c / (1.f + __expf(-z_c));
    yout[base + (size_t)tt * DIN] = f2bf((y + x_c * dsk) * sz);
    dt_c = dt_n; x_c = x_n; z_c = z_n;
  }
}

#define IN_SZ (3072 * 768)
#define OUT_SZ (768 * 1536)
#define XP_SZ (128 * 1536)
#define DT_SZ (1536 * 64)
#define WTOT (IN_SZ + OUT_SZ + XP_SZ + DT_SZ)

extern "C" void kernel_launch(void* const* d_in, const int* in_sizes, int n_in,
                              void* d_out, int out_size, void* d_ws, size_t ws_size,
                              hipStream_t stream) {
  const int* tokens = (const int*)d_in[0];
  const float* embed = (const float*)d_in[2];
  const float* in_norm_w = (const float*)d_in[3];
  const float* out_norm_w = (const float*)d_in[4];
  const float* norm_f_w = (const float*)d_in[5];
  const float* ln_w = (const float*)d_in[6];
  const float* in_w = (const float*)d_in[7];
  const float* conv_w = (const float*)d_in[8];
  const float* conv_b = (const float*)d_in[9];
  const float* xp_w = (const float*)d_in[10];
  const float* dt_w = (const float*)d_in[11];
  const float* dt_b = (const float*)d_in[12];
  const float* A_log = (const float*)d_in[13];
  const float* D_skip = (const float*)d_in[14];
  const float* out_w = (const float*)d_in[15];
  float* out = (float*)d_out;

  // workspace layout in FLOAT units. bf16 activation buffers hold
  // 8192*1536 = 12,582,912 shorts = 6,291,456 floats each (R3-R5 bug: 3,145,728).
  // Total = 52,133,888 floats = 208.5 MB.
  float* ws = (float*)d_ws;
  float* c = ws;                          // 6291456
  float* xnreg = c + 6291456;             // 3342336 (xn_bf 3145728 | cstate+csumdt)
  float* hbuf = xnreg + 3342336;          // 12582912 (h f32 [8192][1536])
  float* zreg = hbuf + 12582912;          // 6291456 (z bf16 [8192][1536])
  float* hcreg = zreg + 6291456;          // 6291456 (hconv bf16)
  float* ssm = hcreg + 6291456;           // 655360 (ssm f32 [8192][80])
  float* sdtreg = ssm + 655360;           // 262144 (ssm_dt bf16 [8192][64])
  float* dtreg = sdtreg + 262144;         // 6291456 (dt bf16)
  float* yreg = dtreg + 6291456;          // 6291456 (y bf16)
  float* wreg = yreg + 6291456;           // 3833856 (weights bf16, 2 layers)

  short* xn_bf = (short*)xnreg;
  float* cstate = xnreg;                  // time-disjoint with xn_bf
  float* csumdt = xnreg + 3145728;
  short* z_bf = (short*)zreg;
  short* hconv_bf = (short*)hcreg;
  short* ssm_dt_bf = (short*)sdtreg;
  short* dt_bf = (short*)dtreg;
  short* y_bf = (short*)yreg;
  short* wbf = (short*)wreg;

  embed_rms_k<<<T_TOK, 256, 0, stream>>>(tokens, embed, in_norm_w, c);

  for (int l = 0; l < NLAY; ++l) {
    short* wl = wbf + (size_t)l * WTOT;
    convw_k<<<(IN_SZ + 255) / 256, 256, 0, stream>>>(
        in_w + (size_t)l * IN_SZ, wl, 3072, 768, 3072, 768);
    convw_k<<<(OUT_SZ + 255) / 256, 256, 0, stream>>>(
        out_w + (size_t)l * OUT_SZ, wl + IN_SZ, 768, 1536, 768, 1536);
    convw_k<<<(XP_SZ + 255) / 256, 256, 0, stream>>>(
        xp_w + (size_t)l * 80 * 1536, wl + IN_SZ + OUT_SZ, 80, 1536, 128, 1536);
    convw_k<<<(DT_SZ + 255) / 256, 256, 0, stream>>>(
        dt_w + (size_t)l * 1536 * RKK, wl + IN_SZ + OUT_SZ + XP_SZ, 1536, RKK, 1536, 64);
  }

  for (int l = 0; l < NLAY; ++l) {
    short* wl = wbf + (size_t)l * WTOT;
    short* win = wl;
    short* wout = wl + IN_SZ;
    short* wxp = wl + IN_SZ + OUT_SZ;
    short* wdt = wl + IN_SZ + OUT_SZ + XP_SZ;

    rms_bf_k<<<T_TOK, 256, 0, stream>>>(c, ln_w + l * DIM, xn_bf);
    gemm_bf<4><<<dim3(T_TOK / BM, (2 * DIN) / BN), 256, 0, stream>>>(
        xn_bf, DIM, win, DIM, hbuf, 0, 2 * DIN, DIM, nullptr, z_bf);
    conv_k<<<dim3(DIN / 256, T_TOK), 256, 0, stream>>>(
        hbuf, conv_w + l * DIN * 4, conv_b + l * DIN, hconv_bf);
    gemm_bf<3><<<dim3(T_TOK / BM, 1), 256, 0, stream>>>(
        hconv_bf, DIN, wxp, DIN, ssm, 0, RKK + 2 * NST, DIN, nullptr, ssm_dt_bf);
    gemm_bf<2><<<dim3(T_TOK / BM, DIN / BN), 256, 0, stream>>>(
        ssm_dt_bf, 64, wdt, 64, nullptr, 0, DIN, 64, dt_b + l * DIN, dt_bf);
    scan_p1<<<dim3(DIN / 256, NSEG, NCH), 256, 0, stream>>>(
        dt_bf, hconv_bf, ssm, A_log + (size_t)l * DIN * NST, cstate, csumdt);
    scan_p2<<<(NSEG * DIN * NST) / 256, 256, 0, stream>>>(
        A_log + (size_t)l * DIN * NST, csumdt, cstate);
    scan_p3<<<dim3(DIN / 256, NSEG, NCH), 256, 0, stream>>>(
        dt_bf, hconv_bf, ssm, z_bf, A_log + (size_t)l * DIN * NST, D_skip + l * DIN,
        cstate, y_bf);
    gemm_bf<1><<<dim3(T_TOK / BM, DIM / BN), 256, 0, stream>>>(
        y_bf, DIN, wout, DIN, c, DIM, DIM, DIN, c, nullptr);
  }

  final_norm_k<<<T_TOK, 256, 0, stream>>>(c, norm_f_w, out_norm_w, out);
}

// Round 8
// 808.657 us; speedup vs baseline: 4.7664x; 1.2525x over previous
//
#include <hip/hip_runtime.h>

#define T_TOK 8192
#define DIM 768
#define DIN 1536
#define NST 16
#define RKK 48
#define NLAY 2
#define NSEG 4
#define LSEGC 2048
#define EPSF 1e-5f
#define CHUNK 64
#define NCH (LSEGC / CHUNK)

typedef __attribute__((ext_vector_type(4))) float f32x4;
typedef __attribute__((ext_vector_type(8))) short bf16x8;

__device__ __forceinline__ short f2bf(float x) {
  union { float f; unsigned u; } c; c.f = x;
  unsigned r = (c.u + 0x7fffu + ((c.u >> 16) & 1u)) >> 16;
  return (short)r;
}

__device__ __forceinline__ float bf2f(short s) {
  union { unsigned u; float f; } c;
  c.u = ((unsigned)(unsigned short)s) << 16;
  return c.f;
}

__device__ __forceinline__ void gload16(const short* g, short* l) {
  __builtin_amdgcn_global_load_lds(
      (const __attribute__((address_space(1))) void*)g,
      (__attribute__((address_space(3))) void*)l, 16, 0, 0);
}

__device__ __forceinline__ float wave_sum(float v) {
#pragma unroll
  for (int o = 32; o > 0; o >>= 1) v += __shfl_xor(v, o, 64);
  return v;
}

__device__ __forceinline__ float block_sum(float v, float* sbuf) {
  v = wave_sum(v);
  int w = threadIdx.x >> 6;
  if ((threadIdx.x & 63) == 0) sbuf[w] = v;
  __syncthreads();
  return sbuf[0] + sbuf[1] + sbuf[2] + sbuf[3];
}

__global__ void embed_rms_k(const int* __restrict__ tok, const float* __restrict__ emb,
                            const float* __restrict__ w, float* __restrict__ out) {
  __shared__ float sb[4];
  int t = blockIdx.x, tid = threadIdx.x;
  const float* row = emb + (size_t)tok[t] * DIM;
  float v0 = row[tid], v1 = row[tid + 256], v2 = row[tid + 512];
  float ss = block_sum(v0 * v0 + v1 * v1 + v2 * v2, sb);
  float rs = rsqrtf(ss * (1.f / DIM) + EPSF);
  float* o = out + (size_t)t * DIM;
  o[tid] = v0 * rs * w[tid];
  o[tid + 256] = v1 * rs * w[tid + 256];
  o[tid + 512] = v2 * rs * w[tid + 512];
}

__global__ void rms_bf_k(const float* __restrict__ x, const float* __restrict__ w,
                         short* __restrict__ out) {
  __shared__ float sb[4];
  int t = blockIdx.x, tid = threadIdx.x;
  const float* row = x + (size_t)t * DIM;
  float v0 = row[tid], v1 = row[tid + 256], v2 = row[tid + 512];
  float ss = block_sum(v0 * v0 + v1 * v1 + v2 * v2, sb);
  float rs = rsqrtf(ss * (1.f / DIM) + EPSF);
  short* o = out + (size_t)t * DIM;
  o[tid] = f2bf(v0 * rs * w[tid]);
  o[tid + 256] = f2bf(v1 * rs * w[tid + 256]);
  o[tid + 512] = f2bf(v2 * rs * w[tid + 512]);
}

__global__ void final_norm_k(const float* __restrict__ c, const float* __restrict__ wf,
                             const float* __restrict__ wo, float* __restrict__ out) {
  __shared__ float sb1[4];
  __shared__ float sb2[4];
  int t = blockIdx.x, tid = threadIdx.x;
  const float* row = c + (size_t)t * DIM;
  float v0 = row[tid], v1 = row[tid + 256], v2 = row[tid + 512];
  float ss = block_sum(v0 * v0 + v1 * v1 + v2 * v2, sb1);
  float rs = rsqrtf(ss * (1.f / DIM) + EPSF);
  float y0 = v0 * rs * wf[tid], y1 = v1 * rs * wf[tid + 256], y2 = v2 * rs * wf[tid + 512];
  float ss2 = block_sum(y0 * y0 + y1 * y1 + y2 * y2, sb2);
  float rs2 = rsqrtf(ss2 * (1.f / DIM) + EPSF);
  float* o = out + (size_t)t * DIM;
  o[tid] = y0 * rs2 * wo[tid];
  o[tid + 256] = y1 * rs2 * wo[tid + 256];
  o[tid + 512] = y2 * rs2 * wo[tid + 512];
}

// weight f32 -> bf16 with zero padding to (drows, dcols)
__global__ void convw_k(const float* __restrict__ src, short* __restrict__ dst,
                        int rows, int cols, int drows, int dcols) {
  int i = blockIdx.x * 256 + threadIdx.x;
  if (i >= drows * dcols) return;
  int r = i / dcols, cc = i - r * dcols;
  float v = (r < rows && cc < cols) ? src[(size_t)r * cols + cc] : 0.f;
  dst[i] = f2bf(v);
}

// ------- MFMA NT GEMM, bf16 inputs, global_load_lds staging, both-sides XOR swizzle -------
// C[M][N] = A[M][K] * W[N][K]^T.  M mult of 128, K mult of 64, W rows mult of 128.
// EPI 1: C f32 = acc + aux[idx] (residual)
// EPI 2: out2 bf16 = softplus_fast(acc + aux[col])      (dt GEMM)
// EPI 3: C f32 (N=80) + out2 bf16 padded to 64 cols     (xp GEMM)
// EPI 4: split: col<DIN -> out2 bf16 (h); else out3 bf16 (z)   (in GEMM)
#define BM 128
#define BN 128

template <int EPI>
__global__ __launch_bounds__(256) void gemm_bf(const short* __restrict__ A, int lda,
                                               const short* __restrict__ W, int ldw,
                                               float* __restrict__ C, int ldc, int N, int K,
                                               const float* __restrict__ aux,
                                               short* __restrict__ out2,
                                               short* __restrict__ out3) {
  __shared__ short As[BM * 64];
  __shared__ short Ws[BN * 64];
  const int tid = threadIdx.x;
  const int lane = tid & 63;
  const int wave = tid >> 6;
  const int bm = blockIdx.x * BM;
  const int bn = blockIdx.y * BN;
  const int wr = (wave >> 1) * 64;
  const int wc = (wave & 1) * 64;
  const int lrow = lane >> 3;                 // 0..7
  const int lcol = ((lane & 7) ^ lrow) << 3;  // inverse-swizzled source col (shorts)

  const short* Abase = A + (size_t)(bm + wave * 32 + lrow) * lda + lcol;
  const short* Wbase = W + (size_t)(bn + wave * 32 + lrow) * ldw + lcol;

  f32x4 acc[4][4];
#pragma unroll
  for (int m = 0; m < 4; ++m)
#pragma unroll
    for (int n = 0; n < 4; ++n) acc[m][n] = (f32x4){0.f, 0.f, 0.f, 0.f};

  for (int k0 = 0; k0 < K; k0 += 64) {
#pragma unroll
    for (int j = 0; j < 4; ++j)
      gload16(Abase + (size_t)(j * 8) * lda + k0, As + (wave * 4 + j) * 512);
#pragma unroll
    for (int j = 0; j < 4; ++j)
      gload16(Wbase + (size_t)(j * 8) * ldw + k0, Ws + (wave * 4 + j) * 512);
    __syncthreads();  // drains vmcnt (gload) before any LDS read

    const int r = lane & 15;
    const int swz = (r & 7) << 3;
#pragma unroll
    for (int ks = 0; ks < 64; ks += 32) {
      const int kq = (ks + ((lane >> 4) << 3)) ^ swz;
      bf16x8 af[4], wf[4];
#pragma unroll
      for (int m = 0; m < 4; ++m)
        af[m] = *reinterpret_cast<const bf16x8*>(&As[(wr + m * 16 + r) * 64 + kq]);
#pragma unroll
      for (int n = 0; n < 4; ++n)
        wf[n] = *reinterpret_cast<const bf16x8*>(&Ws[(wc + n * 16 + r) * 64 + kq]);
#pragma unroll
      for (int m = 0; m < 4; ++m)
#pragma unroll
        for (int n = 0; n < 4; ++n)
          acc[m][n] = __builtin_amdgcn_mfma_f32_16x16x32_bf16(af[m], wf[n], acc[m][n], 0, 0, 0);
    }
    __syncthreads();  // readers done before next iter's gload overwrites
  }

  const int r4 = ((lane >> 4) & 3) * 4;
  const int cl = lane & 15;
#pragma unroll
  for (int m = 0; m < 4; ++m) {
    const int row0 = bm + wr + m * 16 + r4;
#pragma unroll
    for (int n = 0; n < 4; ++n) {
      const int col = bn + wc + n * 16 + cl;
#pragma unroll
      for (int r = 0; r < 4; ++r) {
        float v = acc[m][n][r];
        size_t row = (size_t)(row0 + r);
        if (EPI == 1) {
          size_t idx = row * ldc + col;
          C[idx] = v + aux[idx];
        } else if (EPI == 2) {
          v += aux[col];
          // fast softplus: __expf/__logf are v_exp/v_log based (precise log1pf was
          // ~6x the kernel time in R7 profile: VALUBusy 34%, MfmaUtil 0.5%)
          float sp = (v > 15.f) ? v : __logf(1.f + __expf(v));
          out2[row * DIN + col] = f2bf(sp);
        } else if (EPI == 3) {
          if (col < N) C[row * 80 + col] = v;
          if (col < 64) out2[row * 64 + col] = (col < RKK) ? f2bf(v) : 0;
        } else if (EPI == 4) {
          if (col < DIN) out2[row * DIN + col] = f2bf(v);
          else out3[row * DIN + col - DIN] = f2bf(v);
        }
      }
    }
  }
}

// ------- depthwise causal conv (k=4) + bias + silu; bf16 in/out -------
__global__ void conv_k(const short* __restrict__ h, const float* __restrict__ cw,
                       const float* __restrict__ cb, short* __restrict__ outb) {
  int d = blockIdx.x * 256 + threadIdx.x;
  int t = blockIdx.y;
  int tl = t & (LSEGC - 1);
  float s = cb[d];
  const short* col = h + (size_t)t * DIN + d;
#pragma unroll
  for (int k = 0; k < 4; ++k) {
    int ts = tl - 3 + k;
    if (ts >= 0) s += bf2f(col[(ptrdiff_t)(k - 3) * DIN]) * cw[d * 4 + k];
  }
  float y = s / (1.f + __expf(-s));
  outb[(size_t)t * DIN + d] = f2bf(y);
}

// ---------------- chunked selective scan (bf16 dt/x/z inputs) ----------------
__global__ __launch_bounds__(256) void scan_p1(const short* __restrict__ dtb,
                                               const short* __restrict__ xb,
                                               const float* __restrict__ ssm,
                                               const float* __restrict__ A_log,
                                               float* __restrict__ cstate,
                                               float* __restrict__ csumdt) {
  __shared__ float bsh[CHUNK][16];
  const int tid = threadIdx.x;
  const int d = blockIdx.x * 256 + tid;
  const int s = blockIdx.y;
  const int ch = blockIdx.z;
  const int t0 = s * LSEGC + ch * CHUNK;

  {
    int step = tid >> 2, part = tid & 3;
    float4 v = *reinterpret_cast<const float4*>(ssm + (size_t)(t0 + step) * 80 + 48 + part * 4);
    *reinterpret_cast<float4*>(&bsh[step][part * 4]) = v;
  }
  __syncthreads();

  float Areg[NST];
#pragma unroll
  for (int n = 0; n < NST; ++n) Areg[n] = -__expf(A_log[d * NST + n]);
  float st[NST];
#pragma unroll
  for (int n = 0; n < NST; ++n) st[n] = 0.f;
  float sumdt = 0.f;

  size_t base = (size_t)t0 * DIN + d;
  float dt_c = bf2f(dtb[base]), x_c = bf2f(xb[base]);
  for (int tt = 0; tt < CHUNK; ++tt) {
    float dt_n = 0.f, x_n = 0.f;
    if (tt < CHUNK - 1) {
      size_t b2 = base + (size_t)(tt + 1) * DIN;
      dt_n = bf2f(dtb[b2]);
      x_n = bf2f(xb[b2]);
    }
    sumdt += dt_c;
    float dtx = dt_c * x_c;
    const float* br = bsh[tt];
#pragma unroll
    for (int n = 0; n < NST; ++n) st[n] = st[n] * __expf(dt_c * Areg[n]) + dtx * br[n];
    dt_c = dt_n; x_c = x_n;
  }

  size_t cidx = (((size_t)s * NCH + ch) * DIN + d) * NST;
#pragma unroll
  for (int n = 0; n < NST; n += 4)
    *reinterpret_cast<f32x4*>(cstate + cidx + n) = (f32x4){st[n], st[n+1], st[n+2], st[n+3]};
  csumdt[((size_t)s * NCH + ch) * DIN + d] = sumdt;
}

__global__ __launch_bounds__(256) void scan_p2(const float* __restrict__ A_log,
                                               const float* __restrict__ csumdt,
                                               float* __restrict__ cstate) {
  int idx = blockIdx.x * 256 + threadIdx.x;
  int n = idx & (NST - 1);
  int d = (idx / NST) % DIN;
  int s = idx / (DIN * NST);
  float A = -__expf(A_log[d * NST + n]);
  float H = 0.f;
  for (int c = 0; c < NCH; ++c) {
    size_t off = (((size_t)s * NCH + c) * DIN + d) * NST + n;
    float loc = cstate[off];
    float sd = csumdt[((size_t)s * NCH + c) * DIN + d];
    cstate[off] = H;
    H = H * __expf(A * sd) + loc;
  }
}

__global__ __launch_bounds__(256) void scan_p3(const short* __restrict__ dtb,
                                               const short* __restrict__ xb,
                                               const float* __restrict__ ssm,
                                               const short* __restrict__ zb,
                                               const float* __restrict__ A_log,
                                               const float* __restrict__ Dsk,
                                               const float* __restrict__ cstate,
                                               short* __restrict__ yout) {
  __shared__ float bc[CHUNK][32];
  const int tid = threadIdx.x;
  const int d = blockIdx.x * 256 + tid;
  const int s = blockIdx.y;
  const int ch = blockIdx.z;
  const int t0 = s * LSEGC + ch * CHUNK;

#pragma unroll
  for (int rr = 0; rr < 2; ++rr) {
    int i = tid + rr * 256;
    int step = i >> 3, part = i & 7;
    float4 v = *reinterpret_cast<const float4*>(ssm + (size_t)(t0 + step) * 80 + 48 + part * 4);
    *reinterpret_cast<float4*>(&bc[step][part * 4]) = v;
  }
  __syncthreads();

  float Areg[NST];
#pragma unroll
  for (int n = 0; n < NST; ++n) Areg[n] = -__expf(A_log[d * NST + n]);
  const float dsk = Dsk[d];

  float st[NST];
  size_t cidx = (((size_t)s * NCH + ch) * DIN + d) * NST;
#pragma unroll
  for (int n = 0; n < NST; n += 4) {
    f32x4 v = *reinterpret_cast<const f32x4*>(cstate + cidx + n);
    st[n] = v[0]; st[n+1] = v[1]; st[n+2] = v[2]; st[n+3] = v[3];
  }

  size_t base = (size_t)t0 * DIN + d;
  float dt_c = bf2f(dtb[base]), x_c = bf2f(xb[base]), z_c = bf2f(zb[base]);
  for (int tt = 0; tt < CHUNK; ++tt) {
    float dt_n = 0.f, x_n = 0.f, z_n = 0.f;
    if (tt < CHUNK - 1) {
      size_t b2 = base + (size_t)(tt + 1) * DIN;
      dt_n = bf2f(dtb[b2]);
      x_n = bf2f(xb[b2]);
      z_n = bf2f(zb[b2]);
    }
    float dtx = dt_c * x_c;
    const float* br = bc[tt];
    float y = 0.f;
#pragma unroll
    for (int n = 0; n < NST; ++n) {
      st[n] = st[n] * __expf(dt_c * Areg[n]) + dtx * br[n];
      y += st[n] * br[16 + n];
    }
    float sz = z_c / (1.f + __expf(-z_c));
    yout[base + (size_t)tt * DIN] = f2bf((y + x_c * dsk) * sz);
    dt_c = dt_n; x_c = x_n; z_c = z_n;
  }
}

#define IN_SZ (3072 * 768)
#define OUT_SZ (768 * 1536)
#define XP_SZ (128 * 1536)
#define DT_SZ (1536 * 64)
#define WTOT (IN_SZ + OUT_SZ + XP_SZ + DT_SZ)

extern "C" void kernel_launch(void* const* d_in, const int* in_sizes, int n_in,
                              void* d_out, int out_size, void* d_ws, size_t ws_size,
                              hipStream_t stream) {
  const int* tokens = (const int*)d_in[0];
  const float* embed = (const float*)d_in[2];
  const float* in_norm_w = (const float*)d_in[3];
  const float* out_norm_w = (const float*)d_in[4];
  const float* norm_f_w = (const float*)d_in[5];
  const float* ln_w = (const float*)d_in[6];
  const float* in_w = (const float*)d_in[7];
  const float* conv_w = (const float*)d_in[8];
  const float* conv_b = (const float*)d_in[9];
  const float* xp_w = (const float*)d_in[10];
  const float* dt_w = (const float*)d_in[11];
  const float* dt_b = (const float*)d_in[12];
  const float* A_log = (const float*)d_in[13];
  const float* D_skip = (const float*)d_in[14];
  const float* out_w = (const float*)d_in[15];
  float* out = (float*)d_out;

  // workspace (float units). bf16 activation buffers: 8192*1536 shorts = 6,291,456 floats.
  // Total = 45,841,408 floats = 183 MB (208.5 MB proven available in R7).
  float* ws = (float*)d_ws;
  float* c = ws;                          // 6291456
  float* xnreg = c + 6291456;             // 3342336 (xn_bf | cstate+csumdt overlay)
  float* hreg = xnreg + 3342336;          // 6291456 (h bf16)
  float* zreg = hreg + 6291456;           // 6291456 (z bf16)
  float* hcreg = zreg + 6291456;          // 6291456 (hconv bf16)
  float* ssm = hcreg + 6291456;           // 655360 (ssm f32 [8192][80])
  float* sdtreg = ssm + 655360;           // 262144 (ssm_dt bf16 [8192][64])
  float* dtreg = sdtreg + 262144;         // 6291456 (dt bf16)
  float* yreg = dtreg + 6291456;          // 6291456 (y bf16)
  float* wreg = yreg + 6291456;           // 3833856 (weights bf16, 2 layers)

  short* xn_bf = (short*)xnreg;
  float* cstate = xnreg;                  // time-disjoint with xn_bf
  float* csumdt = xnreg + 3145728;
  short* h_bf = (short*)hreg;
  short* z_bf = (short*)zreg;
  short* hconv_bf = (short*)hcreg;
  short* ssm_dt_bf = (short*)sdtreg;
  short* dt_bf = (short*)dtreg;
  short* y_bf = (short*)yreg;
  short* wbf = (short*)wreg;

  embed_rms_k<<<T_TOK, 256, 0, stream>>>(tokens, embed, in_norm_w, c);

  for (int l = 0; l < NLAY; ++l) {
    short* wl = wbf + (size_t)l * WTOT;
    convw_k<<<(IN_SZ + 255) / 256, 256, 0, stream>>>(
        in_w + (size_t)l * IN_SZ, wl, 3072, 768, 3072, 768);
    convw_k<<<(OUT_SZ + 255) / 256, 256, 0, stream>>>(
        out_w + (size_t)l * OUT_SZ, wl + IN_SZ, 768, 1536, 768, 1536);
    convw_k<<<(XP_SZ + 255) / 256, 256, 0, stream>>>(
        xp_w + (size_t)l * 80 * 1536, wl + IN_SZ + OUT_SZ, 80, 1536, 128, 1536);
    convw_k<<<(DT_SZ + 255) / 256, 256, 0, stream>>>(
        dt_w + (size_t)l * 1536 * RKK, wl + IN_SZ + OUT_SZ + XP_SZ, 1536, RKK, 1536, 64);
  }

  for (int l = 0; l < NLAY; ++l) {
    short* wl = wbf + (size_t)l * WTOT;
    short* win = wl;
    short* wout = wl + IN_SZ;
    short* wxp = wl + IN_SZ + OUT_SZ;
    short* wdt = wl + IN_SZ + OUT_SZ + XP_SZ;

    rms_bf_k<<<T_TOK, 256, 0, stream>>>(c, ln_w + l * DIM, xn_bf);
    gemm_bf<4><<<dim3(T_TOK / BM, (2 * DIN) / BN), 256, 0, stream>>>(
        xn_bf, DIM, win, DIM, nullptr, 0, 2 * DIN, DIM, nullptr, h_bf, z_bf);
    conv_k<<<dim3(DIN / 256, T_TOK), 256, 0, stream>>>(
        h_bf, conv_w + l * DIN * 4, conv_b + l * DIN, hconv_bf);
    gemm_bf<3><<<dim3(T_TOK / BM, 1), 256, 0, stream>>>(
        hconv_bf, DIN, wxp, DIN, ssm, 0, RKK + 2 * NST, DIN, nullptr, ssm_dt_bf, nullptr);
    gemm_bf<2><<<dim3(T_TOK / BM, DIN / BN), 256, 0, stream>>>(
        ssm_dt_bf, 64, wdt, 64, nullptr, 0, DIN, 64, dt_b + l * DIN, dt_bf, nullptr);
    scan_p1<<<dim3(DIN / 256, NSEG, NCH), 256, 0, stream>>>(
        dt_bf, hconv_bf, ssm, A_log + (size_t)l * DIN * NST, cstate, csumdt);
    scan_p2<<<(NSEG * DIN * NST) / 256, 256, 0, stream>>>(
        A_log + (size_t)l * DIN * NST, csumdt, cstate);
    scan_p3<<<dim3(DIN / 256, NSEG, NCH), 256, 0, stream>>>(
        dt_bf, hconv_bf, ssm, z_bf, A_log + (size_t)l * DIN * NST, D_skip + l * DIN,
        cstate, y_bf);
    gemm_bf<1><<<dim3(T_TOK / BM, DIM / BN), 256, 0, stream>>>(
        y_bf, DIN, wout, DIN, c, DIM, DIM, DIN, c, nullptr, nullptr);
  }

  final_norm_k<<<T_TOK, 256, 0, stream>>>(c, norm_f_w, out_norm_w, out);
}

// Round 9
// 731.960 us; speedup vs baseline: 5.2659x; 1.1048x over previous
//
#include <hip/hip_runtime.h>

#define T_TOK 8192
#define DIM 768
#define DIN 1536
#define NST 16
#define RKK 48
#define NLAY 2
#define NSEG 4
#define LSEGC 2048
#define EPSF 1e-5f
#define CHUNK 64
#define NCH (LSEGC / CHUNK)

typedef __attribute__((ext_vector_type(4))) float f32x4;
typedef __attribute__((ext_vector_type(8))) short bf16x8;

__device__ __forceinline__ short f2bf(float x) {
  union { float f; unsigned u; } c; c.f = x;
  unsigned r = (c.u + 0x7fffu + ((c.u >> 16) & 1u)) >> 16;
  return (short)r;
}

__device__ __forceinline__ float bf2f(short s) {
  union { unsigned u; float f; } c;
  c.u = ((unsigned)(unsigned short)s) << 16;
  return c.f;
}

__device__ __forceinline__ void gload16(const short* g, short* l) {
  __builtin_amdgcn_global_load_lds(
      (const __attribute__((address_space(1))) void*)g,
      (__attribute__((address_space(3))) void*)l, 16, 0, 0);
}

__device__ __forceinline__ float wave_sum(float v) {
#pragma unroll
  for (int o = 32; o > 0; o >>= 1) v += __shfl_xor(v, o, 64);
  return v;
}

__device__ __forceinline__ float block_sum(float v, float* sbuf) {
  v = wave_sum(v);
  int w = threadIdx.x >> 6;
  if ((threadIdx.x & 63) == 0) sbuf[w] = v;
  __syncthreads();
  return sbuf[0] + sbuf[1] + sbuf[2] + sbuf[3];
}

__global__ void embed_rms_k(const int* __restrict__ tok, const float* __restrict__ emb,
                            const float* __restrict__ w, float* __restrict__ out) {
  __shared__ float sb[4];
  int t = blockIdx.x, tid = threadIdx.x;
  const float* row = emb + (size_t)tok[t] * DIM;
  float v0 = row[tid], v1 = row[tid + 256], v2 = row[tid + 512];
  float ss = block_sum(v0 * v0 + v1 * v1 + v2 * v2, sb);
  float rs = rsqrtf(ss * (1.f / DIM) + EPSF);
  float* o = out + (size_t)t * DIM;
  o[tid] = v0 * rs * w[tid];
  o[tid + 256] = v1 * rs * w[tid + 256];
  o[tid + 512] = v2 * rs * w[tid + 512];
}

__global__ void rms_bf_k(const float* __restrict__ x, const float* __restrict__ w,
                         short* __restrict__ out) {
  __shared__ float sb[4];
  int t = blockIdx.x, tid = threadIdx.x;
  const float* row = x + (size_t)t * DIM;
  float v0 = row[tid], v1 = row[tid + 256], v2 = row[tid + 512];
  float ss = block_sum(v0 * v0 + v1 * v1 + v2 * v2, sb);
  float rs = rsqrtf(ss * (1.f / DIM) + EPSF);
  short* o = out + (size_t)t * DIM;
  o[tid] = f2bf(v0 * rs * w[tid]);
  o[tid + 256] = f2bf(v1 * rs * w[tid + 256]);
  o[tid + 512] = f2bf(v2 * rs * w[tid + 512]);
}

__global__ void final_norm_k(const float* __restrict__ c, const float* __restrict__ wf,
                             const float* __restrict__ wo, float* __restrict__ out) {
  __shared__ float sb1[4];
  __shared__ float sb2[4];
  int t = blockIdx.x, tid = threadIdx.x;
  const float* row = c + (size_t)t * DIM;
  float v0 = row[tid], v1 = row[tid + 256], v2 = row[tid + 512];
  float ss = block_sum(v0 * v0 + v1 * v1 + v2 * v2, sb1);
  float rs = rsqrtf(ss * (1.f / DIM) + EPSF);
  float y0 = v0 * rs * wf[tid], y1 = v1 * rs * wf[tid + 256], y2 = v2 * rs * wf[tid + 512];
  float ss2 = block_sum(y0 * y0 + y1 * y1 + y2 * y2, sb2);
  float rs2 = rsqrtf(ss2 * (1.f / DIM) + EPSF);
  float* o = out + (size_t)t * DIM;
  o[tid] = y0 * rs2 * wo[tid];
  o[tid + 256] = y1 * rs2 * wo[tid + 256];
  o[tid + 512] = y2 * rs2 * wo[tid + 512];
}

#define IN_SZ (3072 * 768)
#define OUT_SZ (768 * 1536)
#define XP_SZ (128 * 1536)
#define DT_SZ (1536 * 64)
#define WTOT (IN_SZ + OUT_SZ + XP_SZ + DT_SZ)

// fused weight conversion: all 4 weight tensors x NLAY layers, one launch
__global__ void convw_all(const float* __restrict__ in_w, const float* __restrict__ out_w,
                          const float* __restrict__ xp_w, const float* __restrict__ dt_w,
                          short* __restrict__ dst) {
  int i = blockIdx.x * 256 + threadIdx.x;
  if (i >= NLAY * WTOT) return;
  int l = i / WTOT;
  int r = i - l * WTOT;
  float v;
  if (r < IN_SZ) {
    v = in_w[(size_t)l * IN_SZ + r];
  } else if (r < IN_SZ + OUT_SZ) {
    v = out_w[(size_t)l * OUT_SZ + (r - IN_SZ)];
  } else if (r < IN_SZ + OUT_SZ + XP_SZ) {
    int rr = r - (IN_SZ + OUT_SZ);
    int dr = rr / 1536, cc = rr - dr * 1536;
    v = (dr < 80) ? xp_w[((size_t)l * 80 + dr) * 1536 + cc] : 0.f;
  } else {
    int rr = r - (IN_SZ + OUT_SZ + XP_SZ);
    int dr = rr >> 6, cc = rr & 63;
    v = (cc < RKK) ? dt_w[((size_t)l * 1536 + dr) * RKK + cc] : 0.f;
  }
  dst[i] = f2bf(v);
}

// ------- MFMA NT GEMM, bf16 inputs, global_load_lds staging, both-sides XOR swizzle -------
#define BM 128
#define BN 128

template <int EPI>
__global__ __launch_bounds__(256) void gemm_bf(const short* __restrict__ A, int lda,
                                               const short* __restrict__ W, int ldw,
                                               float* __restrict__ C, int ldc, int N, int K,
                                               const float* __restrict__ aux,
                                               short* __restrict__ out2,
                                               short* __restrict__ out3) {
  __shared__ short As[BM * 64];
  __shared__ short Ws[BN * 64];
  const int tid = threadIdx.x;
  const int lane = tid & 63;
  const int wave = tid >> 6;
  const int bm = blockIdx.x * BM;
  const int bn = blockIdx.y * BN;
  const int wr = (wave >> 1) * 64;
  const int wc = (wave & 1) * 64;
  const int lrow = lane >> 3;
  const int lcol = ((lane & 7) ^ lrow) << 3;

  const short* Abase = A + (size_t)(bm + wave * 32 + lrow) * lda + lcol;
  const short* Wbase = W + (size_t)(bn + wave * 32 + lrow) * ldw + lcol;

  f32x4 acc[4][4];
#pragma unroll
  for (int m = 0; m < 4; ++m)
#pragma unroll
    for (int n = 0; n < 4; ++n) acc[m][n] = (f32x4){0.f, 0.f, 0.f, 0.f};

  for (int k0 = 0; k0 < K; k0 += 64) {
#pragma unroll
    for (int j = 0; j < 4; ++j)
      gload16(Abase + (size_t)(j * 8) * lda + k0, As + (wave * 4 + j) * 512);
#pragma unroll
    for (int j = 0; j < 4; ++j)
      gload16(Wbase + (size_t)(j * 8) * ldw + k0, Ws + (wave * 4 + j) * 512);
    __syncthreads();

    const int r = lane & 15;
    const int swz = (r & 7) << 3;
#pragma unroll
    for (int ks = 0; ks < 64; ks += 32) {
      const int kq = (ks + ((lane >> 4) << 3)) ^ swz;
      bf16x8 af[4], wf[4];
#pragma unroll
      for (int m = 0; m < 4; ++m)
        af[m] = *reinterpret_cast<const bf16x8*>(&As[(wr + m * 16 + r) * 64 + kq]);
#pragma unroll
      for (int n = 0; n < 4; ++n)
        wf[n] = *reinterpret_cast<const bf16x8*>(&Ws[(wc + n * 16 + r) * 64 + kq]);
#pragma unroll
      for (int m = 0; m < 4; ++m)
#pragma unroll
        for (int n = 0; n < 4; ++n)
          acc[m][n] = __builtin_amdgcn_mfma_f32_16x16x32_bf16(af[m], wf[n], acc[m][n], 0, 0, 0);
    }
    __syncthreads();
  }

  const int r4 = ((lane >> 4) & 3) * 4;
  const int cl = lane & 15;
#pragma unroll
  for (int m = 0; m < 4; ++m) {
    const int row0 = bm + wr + m * 16 + r4;
#pragma unroll
    for (int n = 0; n < 4; ++n) {
      const int col = bn + wc + n * 16 + cl;
#pragma unroll
      for (int r = 0; r < 4; ++r) {
        float v = acc[m][n][r];
        size_t row = (size_t)(row0 + r);
        if (EPI == 1) {
          size_t idx = row * ldc + col;
          C[idx] = v + aux[idx];
        } else if (EPI == 2) {
          v += aux[col];
          float sp = (v > 15.f) ? v : __logf(1.f + __expf(v));
          out2[row * DIN + col] = f2bf(sp);
        } else if (EPI == 3) {
          if (col < N) C[row * 80 + col] = v;
          if (col < 64) out2[row * 64 + col] = (col < RKK) ? f2bf(v) : 0;
        } else if (EPI == 4) {
          if (col < DIN) out2[row * DIN + col] = f2bf(v);
          else out3[row * DIN + col - DIN] = f2bf(v);
        }
      }
    }
  }
}

// ------- depthwise causal conv (k=4) + bias + silu; bf16 in/out -------
__global__ void conv_k(const short* __restrict__ h, const float* __restrict__ cw,
                       const float* __restrict__ cb, short* __restrict__ outb) {
  int d = blockIdx.x * 256 + threadIdx.x;
  int t = blockIdx.y;
  int tl = t & (LSEGC - 1);
  float s = cb[d];
  const short* col = h + (size_t)t * DIN + d;
#pragma unroll
  for (int k = 0; k < 4; ++k) {
    int ts = tl - 3 + k;
    if (ts >= 0) s += bf2f(col[(ptrdiff_t)(k - 3) * DIN]) * cw[d * 4 + k];
  }
  float y = s / (1.f + __expf(-s));
  outb[(size_t)t * DIN + d] = f2bf(y);
}

// ---------------- chunked selective scan ----------------
// Decay structure: A[n] = -exp(A_log[n]); for this model A_log = log(1..16) so
// A[n] = -(n+1) and exp(dt*A[n]) = e1^(n+1), e1 = exp(-dt): 1 exp + 15 muls
// instead of 16 exps. Wave-uniform guard falls back to generic exp2 path.
__device__ __forceinline__ bool a_is_integer(const float* Areg) {
  bool ok = true;
#pragma unroll
  for (int n = 0; n < NST; ++n)
    ok = ok && (fabsf(Areg[n] + (float)(n + 1)) < 1e-3f * (n + 1));
  return ok;
}

__global__ __launch_bounds__(256) void scan_p1(const short* __restrict__ dtb,
                                               const short* __restrict__ xb,
                                               const float* __restrict__ ssm,
                                               const float* __restrict__ A_log,
                                               float* __restrict__ cstate,
                                               float* __restrict__ csumdt) {
  __shared__ float bsh[CHUNK][16];
  const int tid = threadIdx.x;
  const int d = blockIdx.x * 256 + tid;
  const int s = blockIdx.y;
  const int ch = blockIdx.z;
  const int t0 = s * LSEGC + ch * CHUNK;

  {
    int step = tid >> 2, part = tid & 3;
    float4 v = *reinterpret_cast<const float4*>(ssm + (size_t)(t0 + step) * 80 + 48 + part * 4);
    *reinterpret_cast<float4*>(&bsh[step][part * 4]) = v;
  }
  __syncthreads();

  float Areg[NST];
#pragma unroll
  for (int n = 0; n < NST; ++n) Areg[n] = -__expf(A_log[d * NST + n]);
  float st[NST];
#pragma unroll
  for (int n = 0; n < NST; ++n) st[n] = 0.f;
  float sumdt = 0.f;

  size_t base = (size_t)t0 * DIN + d;
  const bool fastA = a_is_integer(Areg);

  if (fastA) {
    float dt_c = bf2f(dtb[base]), x_c = bf2f(xb[base]);
    for (int tt = 0; tt < CHUNK; ++tt) {
      float dt_n = 0.f, x_n = 0.f;
      if (tt < CHUNK - 1) {
        size_t b2 = base + (size_t)(tt + 1) * DIN;
        dt_n = bf2f(dtb[b2]);
        x_n = bf2f(xb[b2]);
      }
      sumdt += dt_c;
      float dtx = dt_c * x_c;
      float Bv[16];
#pragma unroll
      for (int q = 0; q < 4; ++q)
        *reinterpret_cast<f32x4*>(&Bv[q * 4]) = *reinterpret_cast<const f32x4*>(&bsh[tt][q * 4]);
      float e1 = __expf(-dt_c);
      float p = e1;
#pragma unroll
      for (int n = 0; n < NST; ++n) {
        st[n] = st[n] * p + dtx * Bv[n];
        p *= e1;
      }
      dt_c = dt_n; x_c = x_n;
    }
  } else {
    float A2[NST];
#pragma unroll
    for (int n = 0; n < NST; ++n) A2[n] = Areg[n] * 1.442695041f;
    float dt_c = bf2f(dtb[base]), x_c = bf2f(xb[base]);
    for (int tt = 0; tt < CHUNK; ++tt) {
      float dt_n = 0.f, x_n = 0.f;
      if (tt < CHUNK - 1) {
        size_t b2 = base + (size_t)(tt + 1) * DIN;
        dt_n = bf2f(dtb[b2]);
        x_n = bf2f(xb[b2]);
      }
      sumdt += dt_c;
      float dtx = dt_c * x_c;
      float Bv[16];
#pragma unroll
      for (int q = 0; q < 4; ++q)
        *reinterpret_cast<f32x4*>(&Bv[q * 4]) = *reinterpret_cast<const f32x4*>(&bsh[tt][q * 4]);
#pragma unroll
      for (int n = 0; n < NST; ++n)
        st[n] = st[n] * exp2f(dt_c * A2[n]) + dtx * Bv[n];
      dt_c = dt_n; x_c = x_n;
    }
  }

  size_t cidx = (((size_t)s * NCH + ch) * DIN + d) * NST;
#pragma unroll
  for (int n = 0; n < NST; n += 4)
    *reinterpret_cast<f32x4*>(cstate + cidx + n) = (f32x4){st[n], st[n+1], st[n+2], st[n+3]};
  csumdt[((size_t)s * NCH + ch) * DIN + d] = sumdt;
}

__global__ __launch_bounds__(256) void scan_p2(const float* __restrict__ A_log,
                                               const float* __restrict__ csumdt,
                                               float* __restrict__ cstate) {
  int idx = blockIdx.x * 256 + threadIdx.x;
  int n = idx & (NST - 1);
  int d = (idx / NST) % DIN;
  int s = idx / (DIN * NST);
  float A = -__expf(A_log[d * NST + n]);
  float H = 0.f;
  for (int c = 0; c < NCH; ++c) {
    size_t off = (((size_t)s * NCH + c) * DIN + d) * NST + n;
    float loc = cstate[off];
    float sd = csumdt[((size_t)s * NCH + c) * DIN + d];
    cstate[off] = H;
    H = H * __expf(A * sd) + loc;
  }
}

__global__ __launch_bounds__(256) void scan_p3(const short* __restrict__ dtb,
                                               const short* __restrict__ xb,
                                               const float* __restrict__ ssm,
                                               const short* __restrict__ zb,
                                               const float* __restrict__ A_log,
                                               const float* __restrict__ Dsk,
                                               const float* __restrict__ cstate,
                                               short* __restrict__ yout) {
  __shared__ float bc[CHUNK][32];
  const int tid = threadIdx.x;
  const int d = blockIdx.x * 256 + tid;
  const int s = blockIdx.y;
  const int ch = blockIdx.z;
  const int t0 = s * LSEGC + ch * CHUNK;

#pragma unroll
  for (int rr = 0; rr < 2; ++rr) {
    int i = tid + rr * 256;
    int step = i >> 3, part = i & 7;
    float4 v = *reinterpret_cast<const float4*>(ssm + (size_t)(t0 + step) * 80 + 48 + part * 4);
    *reinterpret_cast<float4*>(&bc[step][part * 4]) = v;
  }
  __syncthreads();

  float Areg[NST];
#pragma unroll
  for (int n = 0; n < NST; ++n) Areg[n] = -__expf(A_log[d * NST + n]);
  const float dsk = Dsk[d];

  float st[NST];
  size_t cidx = (((size_t)s * NCH + ch) * DIN + d) * NST;
#pragma unroll
  for (int n = 0; n < NST; n += 4) {
    f32x4 v = *reinterpret_cast<const f32x4*>(cstate + cidx + n);
    st[n] = v[0]; st[n+1] = v[1]; st[n+2] = v[2]; st[n+3] = v[3];
  }

  size_t base = (size_t)t0 * DIN + d;
  const bool fastA = a_is_integer(Areg);

  if (fastA) {
    float dt_c = bf2f(dtb[base]), x_c = bf2f(xb[base]), z_c = bf2f(zb[base]);
    for (int tt = 0; tt < CHUNK; ++tt) {
      float dt_n = 0.f, x_n = 0.f, z_n = 0.f;
      if (tt < CHUNK - 1) {
        size_t b2 = base + (size_t)(tt + 1) * DIN;
        dt_n = bf2f(dtb[b2]);
        x_n = bf2f(xb[b2]);
        z_n = bf2f(zb[b2]);
      }
      float dtx = dt_c * x_c;
      float Bv[16], Cv[16];
#pragma unroll
      for (int q = 0; q < 4; ++q) {
        *reinterpret_cast<f32x4*>(&Bv[q * 4]) = *reinterpret_cast<const f32x4*>(&bc[tt][q * 4]);
        *reinterpret_cast<f32x4*>(&Cv[q * 4]) = *reinterpret_cast<const f32x4*>(&bc[tt][16 + q * 4]);
      }
      float e1 = __expf(-dt_c);
      float p = e1, y = 0.f;
#pragma unroll
      for (int n = 0; n < NST; ++n) {
        st[n] = st[n] * p + dtx * Bv[n];
        y += st[n] * Cv[n];
        p *= e1;
      }
      float sz = z_c / (1.f + __expf(-z_c));
      yout[base + (size_t)tt * DIN] = f2bf((y + x_c * dsk) * sz);
      dt_c = dt_n; x_c = x_n; z_c = z_n;
    }
  } else {
    float A2[NST];
#pragma unroll
    for (int n = 0; n < NST; ++n) A2[n] = Areg[n] * 1.442695041f;
    float dt_c = bf2f(dtb[base]), x_c = bf2f(xb[base]), z_c = bf2f(zb[base]);
    for (int tt = 0; tt < CHUNK; ++tt) {
      float dt_n = 0.f, x_n = 0.f, z_n = 0.f;
      if (tt < CHUNK - 1) {
        size_t b2 = base + (size_t)(tt + 1) * DIN;
        dt_n = bf2f(dtb[b2]);
        x_n = bf2f(xb[b2]);
        z_n = bf2f(zb[b2]);
      }
      float dtx = dt_c * x_c;
      float Bv[16], Cv[16];
#pragma unroll
      for (int q = 0; q < 4; ++q) {
        *reinterpret_cast<f32x4*>(&Bv[q * 4]) = *reinterpret_cast<const f32x4*>(&bc[tt][q * 4]);
        *reinterpret_cast<f32x4*>(&Cv[q * 4]) = *reinterpret_cast<const f32x4*>(&bc[tt][16 + q * 4]);
      }
      float y = 0.f;
#pragma unroll
      for (int n = 0; n < NST; ++n) {
        st[n] = st[n] * exp2f(dt_c * A2[n]) + dtx * Bv[n];
        y += st[n] * Cv[n];
      }
      float sz = z_c / (1.f + __expf(-z_c));
      yout[base + (size_t)tt * DIN] = f2bf((y + x_c * dsk) * sz);
      dt_c = dt_n; x_c = x_n; z_c = z_n;
    }
  }
}

extern "C" void kernel_launch(void* const* d_in, const int* in_sizes, int n_in,
                              void* d_out, int out_size, void* d_ws, size_t ws_size,
                              hipStream_t stream) {
  const int* tokens = (const int*)d_in[0];
  const float* embed = (const float*)d_in[2];
  const float* in_norm_w = (const float*)d_in[3];
  const float* out_norm_w = (const float*)d_in[4];
  const float* norm_f_w = (const float*)d_in[5];
  const float* ln_w = (const float*)d_in[6];
  const float* in_w = (const float*)d_in[7];
  const float* conv_w = (const float*)d_in[8];
  const float* conv_b = (const float*)d_in[9];
  const float* xp_w = (const float*)d_in[10];
  const float* dt_w = (const float*)d_in[11];
  const float* dt_b = (const float*)d_in[12];
  const float* A_log = (const float*)d_in[13];
  const float* D_skip = (const float*)d_in[14];
  const float* out_w = (const float*)d_in[15];
  float* out = (float*)d_out;

  // workspace (float units), total 45,841,408 floats = 183 MB
  float* ws = (float*)d_ws;
  float* c = ws;                          // 6291456
  float* xnreg = c + 6291456;             // 3342336 (xn_bf | cstate+csumdt overlay)
  float* hreg = xnreg + 3342336;          // 6291456 (h bf16)
  float* zreg = hreg + 6291456;           // 6291456 (z bf16)
  float* hcreg = zreg + 6291456;          // 6291456 (hconv bf16)
  float* ssm = hcreg + 6291456;           // 655360 (ssm f32 [8192][80])
  float* sdtreg = ssm + 655360;           // 262144 (ssm_dt bf16 [8192][64])
  float* dtreg = sdtreg + 262144;         // 6291456 (dt bf16)
  float* yreg = dtreg + 6291456;          // 6291456 (y bf16)
  float* wreg = yreg + 6291456;           // 3833856 (weights bf16, 2 layers)

  short* xn_bf = (short*)xnreg;
  float* cstate = xnreg;                  // time-disjoint with xn_bf
  float* csumdt = xnreg + 3145728;
  short* h_bf = (short*)hreg;
  short* z_bf = (short*)zreg;
  short* hconv_bf = (short*)hcreg;
  short* ssm_dt_bf = (short*)sdtreg;
  short* dt_bf = (short*)dtreg;
  short* y_bf = (short*)yreg;
  short* wbf = (short*)wreg;

  embed_rms_k<<<T_TOK, 256, 0, stream>>>(tokens, embed, in_norm_w, c);

  convw_all<<<(NLAY * WTOT + 255) / 256, 256, 0, stream>>>(in_w, out_w, xp_w, dt_w, wbf);

  for (int l = 0; l < NLAY; ++l) {
    short* wl = wbf + (size_t)l * WTOT;
    short* win = wl;
    short* wout = wl + IN_SZ;
    short* wxp = wl + IN_SZ + OUT_SZ;
    short* wdt = wl + IN_SZ + OUT_SZ + XP_SZ;

    rms_bf_k<<<T_TOK, 256, 0, stream>>>(c, ln_w + l * DIM, xn_bf);
    gemm_bf<4><<<dim3(T_TOK / BM, (2 * DIN) / BN), 256, 0, stream>>>(
        xn_bf, DIM, win, DIM, nullptr, 0, 2 * DIN, DIM, nullptr, h_bf, z_bf);
    conv_k<<<dim3(DIN / 256, T_TOK), 256, 0, stream>>>(
        h_bf, conv_w + l * DIN * 4, conv_b + l * DIN, hconv_bf);
    gemm_bf<3><<<dim3(T_TOK / BM, 1), 256, 0, stream>>>(
        hconv_bf, DIN, wxp, DIN, ssm, 0, RKK + 2 * NST, DIN, nullptr, ssm_dt_bf, nullptr);
    gemm_bf<2><<<dim3(T_TOK / BM, DIN / BN), 256, 0, stream>>>(
        ssm_dt_bf, 64, wdt, 64, nullptr, 0, DIN, 64, dt_b + l * DIN, dt_bf, nullptr);
    scan_p1<<<dim3(DIN / 256, NSEG, NCH), 256, 0, stream>>>(
        dt_bf, hconv_bf, ssm, A_log + (size_t)l * DIN * NST, cstate, csumdt);
    scan_p2<<<(NSEG * DIN * NST) / 256, 256, 0, stream>>>(
        A_log + (size_t)l * DIN * NST, csumdt, cstate);
    scan_p3<<<dim3(DIN / 256, NSEG, NCH), 256, 0, stream>>>(
        dt_bf, hconv_bf, ssm, z_bf, A_log + (size_t)l * DIN * NST, D_skip + l * DIN,
        cstate, y_bf);
    gemm_bf<1><<<dim3(T_TOK / BM, DIM / BN), 256, 0, stream>>>(
        y_bf, DIN, wout, DIN, c, DIM, DIM, DIN, c, nullptr, nullptr);
  }

  final_norm_k<<<T_TOK, 256, 0, stream>>>(c, norm_f_w, out_norm_w, out);
}

// Round 10
// 657.463 us; speedup vs baseline: 5.8626x; 1.1133x over previous
//
#include <hip/hip_runtime.h>

#define T_TOK 8192
#define DIM 768
#define DIN 1536
#define NST 16
#define RKK 48
#define NLAY 2
#define NSEG 4
#define LSEGC 2048
#define EPSF 1e-5f
#define CHUNK 64
#define NCH (LSEGC / CHUNK)

typedef __attribute__((ext_vector_type(4))) float f32x4;
typedef __attribute__((ext_vector_type(8))) short bf16x8;

__device__ __forceinline__ short f2bf(float x) {
  union { float f; unsigned u; } c; c.f = x;
  unsigned r = (c.u + 0x7fffu + ((c.u >> 16) & 1u)) >> 16;
  return (short)r;
}

__device__ __forceinline__ float bf2f(short s) {
  union { unsigned u; float f; } c;
  c.u = ((unsigned)(unsigned short)s) << 16;
  return c.f;
}

__device__ __forceinline__ void gload16(const short* g, short* l) {
  __builtin_amdgcn_global_load_lds(
      (const __attribute__((address_space(1))) void*)g,
      (__attribute__((address_space(3))) void*)l, 16, 0, 0);
}

__device__ __forceinline__ float wave_sum(float v) {
#pragma unroll
  for (int o = 32; o > 0; o >>= 1) v += __shfl_xor(v, o, 64);
  return v;
}

__device__ __forceinline__ float block_sum(float v, float* sbuf) {
  v = wave_sum(v);
  int w = threadIdx.x >> 6;
  if ((threadIdx.x & 63) == 0) sbuf[w] = v;
  __syncthreads();
  return sbuf[0] + sbuf[1] + sbuf[2] + sbuf[3];
}

__global__ void embed_rms_k(const int* __restrict__ tok, const float* __restrict__ emb,
                            const float* __restrict__ w, float* __restrict__ out) {
  __shared__ float sb[4];
  int t = blockIdx.x, tid = threadIdx.x;
  const float* row = emb + (size_t)tok[t] * DIM;
  float v0 = row[tid], v1 = row[tid + 256], v2 = row[tid + 512];
  float ss = block_sum(v0 * v0 + v1 * v1 + v2 * v2, sb);
  float rs = rsqrtf(ss * (1.f / DIM) + EPSF);
  float* o = out + (size_t)t * DIM;
  o[tid] = v0 * rs * w[tid];
  o[tid + 256] = v1 * rs * w[tid + 256];
  o[tid + 512] = v2 * rs * w[tid + 512];
}

__global__ void rms_bf_k(const float* __restrict__ x, const float* __restrict__ w,
                         short* __restrict__ out) {
  __shared__ float sb[4];
  int t = blockIdx.x, tid = threadIdx.x;
  const float* row = x + (size_t)t * DIM;
  float v0 = row[tid], v1 = row[tid + 256], v2 = row[tid + 512];
  float ss = block_sum(v0 * v0 + v1 * v1 + v2 * v2, sb);
  float rs = rsqrtf(ss * (1.f / DIM) + EPSF);
  short* o = out + (size_t)t * DIM;
  o[tid] = f2bf(v0 * rs * w[tid]);
  o[tid + 256] = f2bf(v1 * rs * w[tid + 256]);
  o[tid + 512] = f2bf(v2 * rs * w[tid + 512]);
}

__global__ void final_norm_k(const float* __restrict__ c, const float* __restrict__ wf,
                             const float* __restrict__ wo, float* __restrict__ out) {
  __shared__ float sb1[4];
  __shared__ float sb2[4];
  int t = blockIdx.x, tid = threadIdx.x;
  const float* row = c + (size_t)t * DIM;
  float v0 = row[tid], v1 = row[tid + 256], v2 = row[tid + 512];
  float ss = block_sum(v0 * v0 + v1 * v1 + v2 * v2, sb1);
  float rs = rsqrtf(ss * (1.f / DIM) + EPSF);
  float y0 = v0 * rs * wf[tid], y1 = v1 * rs * wf[tid + 256], y2 = v2 * rs * wf[tid + 512];
  float ss2 = block_sum(y0 * y0 + y1 * y1 + y2 * y2, sb2);
  float rs2 = rsqrtf(ss2 * (1.f / DIM) + EPSF);
  float* o = out + (size_t)t * DIM;
  o[tid] = y0 * rs2 * wo[tid];
  o[tid + 256] = y1 * rs2 * wo[tid + 256];
  o[tid + 512] = y2 * rs2 * wo[tid + 512];
}

#define IN_SZ (3072 * 768)
#define OUT_SZ (768 * 1536)
#define XP_SZ (128 * 1536)
#define DT_SZ (1536 * 64)
#define WTOT (IN_SZ + OUT_SZ + XP_SZ + DT_SZ)

// fused weight conversion: all 4 weight tensors x NLAY layers, one launch
__global__ void convw_all(const float* __restrict__ in_w, const float* __restrict__ out_w,
                          const float* __restrict__ xp_w, const float* __restrict__ dt_w,
                          short* __restrict__ dst) {
  int i = blockIdx.x * 256 + threadIdx.x;
  if (i >= NLAY * WTOT) return;
  int l = i / WTOT;
  int r = i - l * WTOT;
  float v;
  if (r < IN_SZ) {
    v = in_w[(size_t)l * IN_SZ + r];
  } else if (r < IN_SZ + OUT_SZ) {
    v = out_w[(size_t)l * OUT_SZ + (r - IN_SZ)];
  } else if (r < IN_SZ + OUT_SZ + XP_SZ) {
    int rr = r - (IN_SZ + OUT_SZ);
    int dr = rr / 1536, cc = rr - dr * 1536;
    v = (dr < 80) ? xp_w[((size_t)l * 80 + dr) * 1536 + cc] : 0.f;
  } else {
    int rr = r - (IN_SZ + OUT_SZ + XP_SZ);
    int dr = rr >> 6, cc = rr & 63;
    v = (cc < RKK) ? dt_w[((size_t)l * 1536 + dr) * RKK + cc] : 0.f;
  }
  dst[i] = f2bf(v);
}

// conv weight transpose: cw[l][d][k] -> cwt[l][k][d]
__global__ void convt_k(const float* __restrict__ cw, float* __restrict__ cwt) {
  int i = blockIdx.x * 256 + threadIdx.x;
  if (i >= NLAY * 4 * DIN) return;
  int l = i / (4 * DIN);
  int r = i - l * 4 * DIN;
  int k = r / DIN, d = r - k * DIN;
  cwt[i] = cw[((size_t)l * DIN + d) * 4 + k];
}

// ------- MFMA NT GEMM, bf16 inputs, global_load_lds staging, both-sides XOR swizzle -------
#define BM 128
#define BN 128

template <int EPI>
__global__ __launch_bounds__(256) void gemm_bf(const short* __restrict__ A, int lda,
                                               const short* __restrict__ W, int ldw,
                                               float* __restrict__ C, int ldc, int N, int K,
                                               const float* __restrict__ aux,
                                               short* __restrict__ out2,
                                               short* __restrict__ out3) {
  __shared__ short As[BM * 64];
  __shared__ short Ws[BN * 64];
  const int tid = threadIdx.x;
  const int lane = tid & 63;
  const int wave = tid >> 6;
  const int bm = blockIdx.x * BM;
  const int bn = blockIdx.y * BN;
  const int wr = (wave >> 1) * 64;
  const int wc = (wave & 1) * 64;
  const int lrow = lane >> 3;
  const int lcol = ((lane & 7) ^ lrow) << 3;

  const short* Abase = A + (size_t)(bm + wave * 32 + lrow) * lda + lcol;
  const short* Wbase = W + (size_t)(bn + wave * 32 + lrow) * ldw + lcol;

  f32x4 acc[4][4];
#pragma unroll
  for (int m = 0; m < 4; ++m)
#pragma unroll
    for (int n = 0; n < 4; ++n) acc[m][n] = (f32x4){0.f, 0.f, 0.f, 0.f};

  for (int k0 = 0; k0 < K; k0 += 64) {
#pragma unroll
    for (int j = 0; j < 4; ++j)
      gload16(Abase + (size_t)(j * 8) * lda + k0, As + (wave * 4 + j) * 512);
#pragma unroll
    for (int j = 0; j < 4; ++j)
      gload16(Wbase + (size_t)(j * 8) * ldw + k0, Ws + (wave * 4 + j) * 512);
    __syncthreads();

    const int r = lane & 15;
    const int swz = (r & 7) << 3;
#pragma unroll
    for (int ks = 0; ks < 64; ks += 32) {
      const int kq = (ks + ((lane >> 4) << 3)) ^ swz;
      bf16x8 af[4], wf[4];
#pragma unroll
      for (int m = 0; m < 4; ++m)
        af[m] = *reinterpret_cast<const bf16x8*>(&As[(wr + m * 16 + r) * 64 + kq]);
#pragma unroll
      for (int n = 0; n < 4; ++n)
        wf[n] = *reinterpret_cast<const bf16x8*>(&Ws[(wc + n * 16 + r) * 64 + kq]);
#pragma unroll
      for (int m = 0; m < 4; ++m)
#pragma unroll
        for (int n = 0; n < 4; ++n)
          acc[m][n] = __builtin_amdgcn_mfma_f32_16x16x32_bf16(af[m], wf[n], acc[m][n], 0, 0, 0);
    }
    __syncthreads();
  }

  const int r4 = ((lane >> 4) & 3) * 4;
  const int cl = lane & 15;
#pragma unroll
  for (int m = 0; m < 4; ++m) {
    const int row0 = bm + wr + m * 16 + r4;
#pragma unroll
    for (int n = 0; n < 4; ++n) {
      const int col = bn + wc + n * 16 + cl;
#pragma unroll
      for (int r = 0; r < 4; ++r) {
        float v = acc[m][n][r];
        size_t row = (size_t)(row0 + r);
        if (EPI == 1) {
          size_t idx = row * ldc + col;
          C[idx] = v + aux[idx];
        } else if (EPI == 2) {
          v += aux[col];
          float sp = (v > 15.f) ? v : __logf(1.f + __expf(v));
          out2[row * DIN + col] = f2bf(sp);
        } else if (EPI == 3) {
          if (col < N) C[row * 80 + col] = v;
          if (col < 64) out2[row * 64 + col] = (col < RKK) ? f2bf(v) : 0;
        } else if (EPI == 4) {
          if (col < DIN) out2[row * DIN + col] = f2bf(v);
          else out3[row * DIN + col - DIN] = f2bf(v);
        }
      }
    }
  }
}

// ------- vectorized depthwise causal conv (k=4) + bias + silu -------
// thread = 8 channels x 4 timesteps; bf16x8 loads/stores, transposed weights.
__global__ __launch_bounds__(192) void conv_vk(const short* __restrict__ h,
                                               const float* __restrict__ cwt,
                                               const float* __restrict__ cb,
                                               short* __restrict__ outb) {
  const int d0 = threadIdx.x * 8;
  const int t0 = blockIdx.x * 4;
  const int tl0 = t0 & (LSEGC - 1);

  float hv[7][8];
#pragma unroll
  for (int r = 0; r < 7; ++r) {
    bool valid = (r >= 3) || (tl0 != 0);
    if (valid) {
      bf16x8 v = *reinterpret_cast<const bf16x8*>(h + (size_t)(t0 - 3 + r) * DIN + d0);
#pragma unroll
      for (int j = 0; j < 8; ++j) hv[r][j] = bf2f(v[j]);
    } else {
#pragma unroll
      for (int j = 0; j < 8; ++j) hv[r][j] = 0.f;
    }
  }
  float w[4][8], b[8];
#pragma unroll
  for (int k = 0; k < 4; ++k) {
    *reinterpret_cast<f32x4*>(&w[k][0]) = *reinterpret_cast<const f32x4*>(cwt + k * DIN + d0);
    *reinterpret_cast<f32x4*>(&w[k][4]) = *reinterpret_cast<const f32x4*>(cwt + k * DIN + d0 + 4);
  }
  *reinterpret_cast<f32x4*>(&b[0]) = *reinterpret_cast<const f32x4*>(cb + d0);
  *reinterpret_cast<f32x4*>(&b[4]) = *reinterpret_cast<const f32x4*>(cb + d0 + 4);

#pragma unroll
  for (int tt = 0; tt < 4; ++tt) {
    short ov[8];
#pragma unroll
    for (int j = 0; j < 8; ++j) {
      float s = b[j];
#pragma unroll
      for (int k = 0; k < 4; ++k) s += hv[tt + k][j] * w[k][j];
      float y = s / (1.f + __expf(-s));
      ov[j] = f2bf(y);
    }
    *reinterpret_cast<bf16x8*>(outb + (size_t)(t0 + tt) * DIN + d0) =
        *reinterpret_cast<bf16x8*>(ov);
  }
}

// ---------------- chunked selective scan ----------------
__device__ __forceinline__ bool a_is_integer(const float* Areg) {
  bool ok = true;
#pragma unroll
  for (int n = 0; n < NST; ++n)
    ok = ok && (fabsf(Areg[n] + (float)(n + 1)) < 1e-3f * (n + 1));
  return ok;
}

__global__ __launch_bounds__(256) void scan_p1(const short* __restrict__ dtb,
                                               const short* __restrict__ xb,
                                               const float* __restrict__ ssm,
                                               const float* __restrict__ A_log,
                                               float* __restrict__ cstate,
                                               float* __restrict__ csumdt) {
  __shared__ float bsh[CHUNK][16];
  const int tid = threadIdx.x;
  const int d = blockIdx.x * 256 + tid;
  const int s = blockIdx.y;
  const int ch = blockIdx.z;
  const int t0 = s * LSEGC + ch * CHUNK;

  {
    int step = tid >> 2, part = tid & 3;
    float4 v = *reinterpret_cast<const float4*>(ssm + (size_t)(t0 + step) * 80 + 48 + part * 4);
    *reinterpret_cast<float4*>(&bsh[step][part * 4]) = v;
  }
  __syncthreads();

  float Areg[NST];
#pragma unroll
  for (int n = 0; n < NST; ++n) Areg[n] = -__expf(A_log[d * NST + n]);
  float st[NST];
#pragma unroll
  for (int n = 0; n < NST; ++n) st[n] = 0.f;
  float sumdt = 0.f;

  size_t base = (size_t)t0 * DIN + d;
  const bool fastA = a_is_integer(Areg);

  if (fastA) {
    float dt_c = bf2f(dtb[base]), x_c = bf2f(xb[base]);
    for (int tt = 0; tt < CHUNK; ++tt) {
      float dt_n = 0.f, x_n = 0.f;
      if (tt < CHUNK - 1) {
        size_t b2 = base + (size_t)(tt + 1) * DIN;
        dt_n = bf2f(dtb[b2]);
        x_n = bf2f(xb[b2]);
      }
      sumdt += dt_c;
      float dtx = dt_c * x_c;
      float Bv[16];
#pragma unroll
      for (int q = 0; q < 4; ++q)
        *reinterpret_cast<f32x4*>(&Bv[q * 4]) = *reinterpret_cast<const f32x4*>(&bsh[tt][q * 4]);
      float e1 = __expf(-dt_c);
      float p = e1;
#pragma unroll
      for (int n = 0; n < NST; ++n) {
        st[n] = st[n] * p + dtx * Bv[n];
        p *= e1;
      }
      dt_c = dt_n; x_c = x_n;
    }
  } else {
    float A2[NST];
#pragma unroll
    for (int n = 0; n < NST; ++n) A2[n] = Areg[n] * 1.442695041f;
    float dt_c = bf2f(dtb[base]), x_c = bf2f(xb[base]);
    for (int tt = 0; tt < CHUNK; ++tt) {
      float dt_n = 0.f, x_n = 0.f;
      if (tt < CHUNK - 1) {
        size_t b2 = base + (size_t)(tt + 1) * DIN;
        dt_n = bf2f(dtb[b2]);
        x_n = bf2f(xb[b2]);
      }
      sumdt += dt_c;
      float dtx = dt_c * x_c;
      float Bv[16];
#pragma unroll
      for (int q = 0; q < 4; ++q)
        *reinterpret_cast<f32x4*>(&Bv[q * 4]) = *reinterpret_cast<const f32x4*>(&bsh[tt][q * 4]);
#pragma unroll
      for (int n = 0; n < NST; ++n)
        st[n] = st[n] * exp2f(dt_c * A2[n]) + dtx * Bv[n];
      dt_c = dt_n; x_c = x_n;
    }
  }

  size_t cidx = (((size_t)s * NCH + ch) * DIN + d) * NST;
#pragma unroll
  for (int n = 0; n < NST; n += 4)
    *reinterpret_cast<f32x4*>(cstate + cidx + n) = (f32x4){st[n], st[n+1], st[n+2], st[n+3]};
  csumdt[((size_t)s * NCH + ch) * DIN + d] = sumdt;
}

__global__ __launch_bounds__(256) void scan_p2(const float* __restrict__ A_log,
                                               const float* __restrict__ csumdt,
                                               float* __restrict__ cstate) {
  int idx = blockIdx.x * 256 + threadIdx.x;
  int n = idx & (NST - 1);
  int d = (idx / NST) % DIN;
  int s = idx / (DIN * NST);
  float A = -__expf(A_log[d * NST + n]);
  float H = 0.f;
  for (int c = 0; c < NCH; ++c) {
    size_t off = (((size_t)s * NCH + c) * DIN + d) * NST + n;
    float loc = cstate[off];
    float sd = csumdt[((size_t)s * NCH + c) * DIN + d];
    cstate[off] = H;
    H = H * __expf(A * sd) + loc;
  }
}

__global__ __launch_bounds__(256) void scan_p3(const short* __restrict__ dtb,
                                               const short* __restrict__ xb,
                                               const float* __restrict__ ssm,
                                               const short* __restrict__ zb,
                                               const float* __restrict__ A_log,
                                               const float* __restrict__ Dsk,
                                               const float* __restrict__ cstate,
                                               short* __restrict__ yout) {
  __shared__ float bc[CHUNK][32];
  const int tid = threadIdx.x;
  const int d = blockIdx.x * 256 + tid;
  const int s = blockIdx.y;
  const int ch = blockIdx.z;
  const int t0 = s * LSEGC + ch * CHUNK;

#pragma unroll
  for (int rr = 0; rr < 2; ++rr) {
    int i = tid + rr * 256;
    int step = i >> 3, part = i & 7;
    float4 v = *reinterpret_cast<const float4*>(ssm + (size_t)(t0 + step) * 80 + 48 + part * 4);
    *reinterpret_cast<float4*>(&bc[step][part * 4]) = v;
  }
  __syncthreads();

  float Areg[NST];
#pragma unroll
  for (int n = 0; n < NST; ++n) Areg[n] = -__expf(A_log[d * NST + n]);
  const float dsk = Dsk[d];

  float st[NST];
  size_t cidx = (((size_t)s * NCH + ch) * DIN + d) * NST;
#pragma unroll
  for (int n = 0; n < NST; n += 4) {
    f32x4 v = *reinterpret_cast<const f32x4*>(cstate + cidx + n);
    st[n] = v[0]; st[n+1] = v[1]; st[n+2] = v[2]; st[n+3] = v[3];
  }

  size_t base = (size_t)t0 * DIN + d;
  const bool fastA = a_is_integer(Areg);

  if (fastA) {
    float dt_c = bf2f(dtb[base]), x_c = bf2f(xb[base]), z_c = bf2f(zb[base]);
    for (int tt = 0; tt < CHUNK; ++tt) {
      float dt_n = 0.f, x_n = 0.f, z_n = 0.f;
      if (tt < CHUNK - 1) {
        size_t b2 = base + (size_t)(tt + 1) * DIN;
        dt_n = bf2f(dtb[b2]);
        x_n = bf2f(xb[b2]);
        z_n = bf2f(zb[b2]);
      }
      float dtx = dt_c * x_c;
      float Bv[16], Cv[16];
#pragma unroll
      for (int q = 0; q < 4; ++q) {
        *reinterpret_cast<f32x4*>(&Bv[q * 4]) = *reinterpret_cast<const f32x4*>(&bc[tt][q * 4]);
        *reinterpret_cast<f32x4*>(&Cv[q * 4]) = *reinterpret_cast<const f32x4*>(&bc[tt][16 + q * 4]);
      }
      float e1 = __expf(-dt_c);
      float p = e1, y = 0.f;
#pragma unroll
      for (int n = 0; n < NST; ++n) {
        st[n] = st[n] * p + dtx * Bv[n];
        y += st[n] * Cv[n];
        p *= e1;
      }
      float sz = z_c / (1.f + __expf(-z_c));
      yout[base + (size_t)tt * DIN] = f2bf((y + x_c * dsk) * sz);
      dt_c = dt_n; x_c = x_n; z_c = z_n;
    }
  } else {
    float A2[NST];
#pragma unroll
    for (int n = 0; n < NST; ++n) A2[n] = Areg[n] * 1.442695041f;
    float dt_c = bf2f(dtb[base]), x_c = bf2f(xb[base]), z_c = bf2f(zb[base]);
    for (int tt = 0; tt < CHUNK; ++tt) {
      float dt_n = 0.f, x_n = 0.f, z_n = 0.f;
      if (tt < CHUNK - 1) {
        size_t b2 = base + (size_t)(tt + 1) * DIN;
        dt_n = bf2f(dtb[b2]);
        x_n = bf2f(xb[b2]);
        z_n = bf2f(zb[b2]);
      }
      float dtx = dt_c * x_c;
      float Bv[16], Cv[16];
#pragma unroll
      for (int q = 0; q < 4; ++q) {
        *reinterpret_cast<f32x4*>(&Bv[q * 4]) = *reinterpret_cast<const f32x4*>(&bc[tt][q * 4]);
        *reinterpret_cast<f32x4*>(&Cv[q * 4]) = *reinterpret_cast<const f32x4*>(&bc[tt][16 + q * 4]);
      }
      float y = 0.f;
#pragma unroll
      for (int n = 0; n < NST; ++n) {
        st[n] = st[n] * exp2f(dt_c * A2[n]) + dtx * Bv[n];
        y += st[n] * Cv[n];
      }
      float sz = z_c / (1.f + __expf(-z_c));
      yout[base + (size_t)tt * DIN] = f2bf((y + x_c * dsk) * sz);
      dt_c = dt_n; x_c = x_n; z_c = z_n;
    }
  }
}

extern "C" void kernel_launch(void* const* d_in, const int* in_sizes, int n_in,
                              void* d_out, int out_size, void* d_ws, size_t ws_size,
                              hipStream_t stream) {
  const int* tokens = (const int*)d_in[0];
  const float* embed = (const float*)d_in[2];
  const float* in_norm_w = (const float*)d_in[3];
  const float* out_norm_w = (const float*)d_in[4];
  const float* norm_f_w = (const float*)d_in[5];
  const float* ln_w = (const float*)d_in[6];
  const float* in_w = (const float*)d_in[7];
  const float* conv_w = (const float*)d_in[8];
  const float* conv_b = (const float*)d_in[9];
  const float* xp_w = (const float*)d_in[10];
  const float* dt_w = (const float*)d_in[11];
  const float* dt_b = (const float*)d_in[12];
  const float* A_log = (const float*)d_in[13];
  const float* D_skip = (const float*)d_in[14];
  const float* out_w = (const float*)d_in[15];
  float* out = (float*)d_out;

  // workspace (float units), total ~45.85M floats = 183 MB
  float* ws = (float*)d_ws;
  float* c = ws;                          // 6291456
  float* xnreg = c + 6291456;             // 3342336 (xn_bf | cstate+csumdt overlay)
  float* hreg = xnreg + 3342336;          // 6291456 (h bf16)
  float* zreg = hreg + 6291456;           // 6291456 (z bf16)
  float* hcreg = zreg + 6291456;          // 6291456 (hconv bf16)
  float* ssm = hcreg + 6291456;           // 655360 (ssm f32 [8192][80])
  float* sdtreg = ssm + 655360;           // 262144 (ssm_dt bf16 [8192][64])
  float* dtreg = sdtreg + 262144;         // 6291456 (dt bf16)
  float* yreg = dtreg + 6291456;          // 6291456 (y bf16)
  float* wreg = yreg + 6291456;           // 3833856 (weights bf16, 2 layers)
  float* cwtreg = wreg + 3833856;         // 12288 (transposed conv weights f32)

  short* xn_bf = (short*)xnreg;
  float* cstate = xnreg;                  // time-disjoint with xn_bf
  float* csumdt = xnreg + 3145728;
  short* h_bf = (short*)hreg;
  short* z_bf = (short*)zreg;
  short* hconv_bf = (short*)hcreg;
  short* ssm_dt_bf = (short*)sdtreg;
  short* dt_bf = (short*)dtreg;
  short* y_bf = (short*)yreg;
  short* wbf = (short*)wreg;

  embed_rms_k<<<T_TOK, 256, 0, stream>>>(tokens, embed, in_norm_w, c);

  convw_all<<<(NLAY * WTOT + 255) / 256, 256, 0, stream>>>(in_w, out_w, xp_w, dt_w, wbf);
  convt_k<<<(NLAY * 4 * DIN + 255) / 256, 256, 0, stream>>>(conv_w, cwtreg);

  for (int l = 0; l < NLAY; ++l) {
    short* wl = wbf + (size_t)l * WTOT;
    short* win = wl;
    short* wout = wl + IN_SZ;
    short* wxp = wl + IN_SZ + OUT_SZ;
    short* wdt = wl + IN_SZ + OUT_SZ + XP_SZ;

    rms_bf_k<<<T_TOK, 256, 0, stream>>>(c, ln_w + l * DIM, xn_bf);
    gemm_bf<4><<<dim3(T_TOK / BM, (2 * DIN) / BN), 256, 0, stream>>>(
        xn_bf, DIM, win, DIM, nullptr, 0, 2 * DIN, DIM, nullptr, h_bf, z_bf);
    conv_vk<<<T_TOK / 4, 192, 0, stream>>>(
        h_bf, cwtreg + (size_t)l * 4 * DIN, conv_b + l * DIN, hconv_bf);
    gemm_bf<3><<<dim3(T_TOK / BM, 1), 256, 0, stream>>>(
        hconv_bf, DIN, wxp, DIN, ssm, 0, RKK + 2 * NST, DIN, nullptr, ssm_dt_bf, nullptr);
    gemm_bf<2><<<dim3(T_TOK / BM, DIN / BN), 256, 0, stream>>>(
        ssm_dt_bf, 64, wdt, 64, nullptr, 0, DIN, 64, dt_b + l * DIN, dt_bf, nullptr);
    scan_p1<<<dim3(DIN / 256, NSEG, NCH), 256, 0, stream>>>(
        dt_bf, hconv_bf, ssm, A_log + (size_t)l * DIN * NST, cstate, csumdt);
    scan_p2<<<(NSEG * DIN * NST) / 256, 256, 0, stream>>>(
        A_log + (size_t)l * DIN * NST, csumdt, cstate);
    scan_p3<<<dim3(DIN / 256, NSEG, NCH), 256, 0, stream>>>(
        dt_bf, hconv_bf, ssm, z_bf, A_log + (size_t)l * DIN * NST, D_skip + l * DIN,
        cstate, y_bf);
    gemm_bf<1><<<dim3(T_TOK / BM, DIM / BN), 256, 0, stream>>>(
        y_bf, DIN, wout, DIN, c, DIM, DIM, DIN, c, nullptr, nullptr);
  }

  final_norm_k<<<T_TOK, 256, 0, stream>>>(c, norm_f_w, out_norm_w, out);
}